// Round 1
// baseline (5480.335 us; speedup 1.0000x reference)
//
#include <hip/hip_runtime.h>
#include <hip/hip_bf16.h>
#include <math.h>

typedef __bf16 bf16;
typedef __bf16 bf16x8 __attribute__((ext_vector_type(8)));
typedef float  f32x4 __attribute__((ext_vector_type(4)));
typedef float  f32x2 __attribute__((ext_vector_type(2)));
typedef unsigned int u32x4 __attribute__((ext_vector_type(4)));

#define NTOK 1024
#define HID  1024
#define NH   16
#define HD   64
#define NL   10
#define QCMAX 256

// epilogue codes
#define EPI_F32        0
#define EPI_BF16       1
#define EPI_RESID      2
#define EPI_SCATTER    3
#define EPI_GELU       4
#define EPI_BIAS_RESID 5

// ---------------------------------------------------------------------------
// Tiled bf16 MFMA GEMM: C[M,N] (+)= A[M,K](bf16) * B[K,N](f32 or bf16)
// 128x128 tile, BK=32, 256 threads (4 waves, 2x2 of 64x64 per wave).
// A staged with global_load_lds (linear row-major [128][32]).
// B reg-staged with f32->bf16 cvt into fragment-major LDS [4][128][8].
// ---------------------------------------------------------------------------
template<int EPI, bool BF32>
__global__ __launch_bounds__(256)
void gemm_k(const bf16* __restrict__ A, int lda, long bsA,
            const void* __restrict__ Bv, int ldb, long bsB,
            void* __restrict__ Cv, int ldc, long bsC,
            const float* __restrict__ bias,
            const int* __restrict__ qidx,
            int M, int N, int K)
{
    __shared__ bf16 Al[128 * 32];     // row-major [128][32]
    __shared__ bf16 Bl[4 * 128 * 8];  // [kgrp][col][8]

    const int t    = threadIdx.x;
    const int lane = t & 63;
    const int wv   = t >> 6;
    const int wr   = wv >> 1, wc = wv & 1;
    const int lrow = lane & 15, lk = lane >> 4;
    const int n0   = blockIdx.x * 128;
    const int m0   = blockIdx.y * 128;
    const int bz   = blockIdx.z;

    const bf16*  Ab = A + bsA * bz;
    const float* Bf = (const float*)Bv + (BF32 ? bsB * bz : 0);
    const bf16*  Bh = (const bf16*)Bv + (BF32 ? 0 : bsB * bz);

    f32x4 acc[4][4];
#pragma unroll
    for (int m = 0; m < 4; ++m)
#pragma unroll
        for (int n = 0; n < 4; ++n) acc[m][n] = f32x4{0.f, 0.f, 0.f, 0.f};

    const int tr = t >> 2, tc = (t & 3) * 8;     // A staging: row, col-chunk
    const int g  = t >> 6, c0 = (t & 63) * 2;    // B staging: k-group, col pair
    const bool cval = (n0 + c0) < N;             // N is a multiple of 64

    for (int k0 = 0; k0 < K; k0 += 32) {
        // ---- stage A (bf16, linear) ----
        {
            const bf16* s0 = Ab + (long)(m0 + tr) * lda + k0 + tc;
            const bf16* s1 = s0 + (long)64 * lda;
            __builtin_amdgcn_global_load_lds(
                (const __attribute__((address_space(1))) void*)s0,
                (__attribute__((address_space(3))) void*)(&Al[t * 8]), 16, 0, 0);
            __builtin_amdgcn_global_load_lds(
                (const __attribute__((address_space(1))) void*)s1,
                (__attribute__((address_space(3))) void*)(&Al[2048 + t * 8]), 16, 0, 0);
        }
        // ---- stage B (cvt to bf16, fragment-major) ----
        {
            bf16x8 w0, w1;
            if (BF32) {
                const float* bp = Bf + (long)(k0 + g * 8) * ldb + n0 + c0;
#pragma unroll
                for (int j = 0; j < 8; ++j) {
                    f32x2 f = {0.f, 0.f};
                    if (cval) f = *(const f32x2*)(bp + (long)j * ldb);
                    w0[j] = (bf16)f.x; w1[j] = (bf16)f.y;
                }
            } else {
                const bf16* bp = Bh + (long)(k0 + g * 8) * ldb + n0 + c0;
#pragma unroll
                for (int j = 0; j < 8; ++j) {
                    bf16 a0 = (bf16)0.f, a1 = (bf16)0.f;
                    if (cval) { a0 = bp[(long)j * ldb]; a1 = bp[(long)j * ldb + 1]; }
                    w0[j] = a0; w1[j] = a1;
                }
            }
            *(bf16x8*)&Bl[(g * 128 + c0) * 8]     = w0;
            *(bf16x8*)&Bl[(g * 128 + c0 + 1) * 8] = w1;
        }
        __syncthreads();

        bf16x8 af[4], bfv[4];
#pragma unroll
        for (int m = 0; m < 4; ++m)
            af[m] = *(const bf16x8*)&Al[(wr * 64 + m * 16 + lrow) * 32 + lk * 8];
#pragma unroll
        for (int n = 0; n < 4; ++n)
            bfv[n] = *(const bf16x8*)&Bl[(lk * 128 + wc * 64 + n * 16 + lrow) * 8];
#pragma unroll
        for (int m = 0; m < 4; ++m)
#pragma unroll
            for (int n = 0; n < 4; ++n)
                acc[m][n] = __builtin_amdgcn_mfma_f32_16x16x32_bf16(af[m], bfv[n], acc[m][n], 0, 0, 0);
        __syncthreads();
    }

    float* Cf = (float*)Cv + bsC * bz;
    bf16*  Cb = (bf16*)Cv + bsC * bz;
#pragma unroll
    for (int m = 0; m < 4; ++m) {
#pragma unroll
        for (int n = 0; n < 4; ++n) {
            int c = n0 + wc * 64 + n * 16 + lrow;
            if (c >= N) continue;
#pragma unroll
            for (int q = 0; q < 4; ++q) {
                int r = m0 + wr * 64 + m * 16 + lk * 4 + q;
                float v = acc[m][n][q];
                long off = (long)r * ldc + c;
                if (EPI == EPI_F32)        Cf[off] = v;
                else if (EPI == EPI_BF16)  Cb[off] = (bf16)v;
                else if (EPI == EPI_RESID) Cf[off] += v;
                else if (EPI == EPI_SCATTER) {
                    int rr = qidx[r];
                    if (rr >= 0) Cf[(long)rr * ldc + c] += v;
                } else if (EPI == EPI_GELU) {
                    float u = v + bias[c];
                    Cb[off] = (bf16)(0.5f * u * (1.f + erff(u * 0.70710678118654752f)));
                } else if (EPI == EPI_BIAS_RESID) {
                    Cf[off] += v + bias[c];
                }
            }
        }
    }
}

// ---------------------------------------------------------------------------
// LayerNorm over rows of 1024 f32 -> bf16 out. One wave per row.
// ---------------------------------------------------------------------------
__global__ __launch_bounds__(256)
void ln_k(const float* __restrict__ x, const float* __restrict__ w,
          const float* __restrict__ b, bf16* __restrict__ o)
{
    int row  = blockIdx.x * 4 + (threadIdx.x >> 6);
    int lane = threadIdx.x & 63;
    const f32x4* xr = (const f32x4*)(x + (long)row * HID) + lane * 4;
    f32x4 v[4];
#pragma unroll
    for (int i = 0; i < 4; ++i) v[i] = xr[i];
    float s = 0.f;
#pragma unroll
    for (int i = 0; i < 4; ++i) s += v[i].x + v[i].y + v[i].z + v[i].w;
    for (int m = 32; m; m >>= 1) s += __shfl_xor(s, m);
    float mean = s * (1.f / 1024.f);
    f32x4 d[4];
    float ss = 0.f;
#pragma unroll
    for (int i = 0; i < 4; ++i) {
        d[i] = v[i] - mean;
        ss += d[i].x * d[i].x + d[i].y * d[i].y + d[i].z * d[i].z + d[i].w * d[i].w;
    }
    for (int m = 32; m; m >>= 1) ss += __shfl_xor(ss, m);
    float rs = rsqrtf(ss * (1.f / 1024.f) + 1e-5f);
    const f32x4* wp = (const f32x4*)w + lane * 4;
    const f32x4* bp = (const f32x4*)b + lane * 4;
    bf16x8 o0, o1;
#pragma unroll
    for (int i = 0; i < 4; ++i) {
        f32x4 wv = wp[i], bv = bp[i];
        f32x4 e;
        e.x = d[i].x * rs * wv.x + bv.x; e.y = d[i].y * rs * wv.y + bv.y;
        e.z = d[i].z * rs * wv.z + bv.z; e.w = d[i].w * rs * wv.w + bv.w;
        if (i < 2) { o0[i*4+0]=(bf16)e.x; o0[i*4+1]=(bf16)e.y; o0[i*4+2]=(bf16)e.z; o0[i*4+3]=(bf16)e.w; }
        else       { int k=(i-2)*4; o1[k+0]=(bf16)e.x; o1[k+1]=(bf16)e.y; o1[k+2]=(bf16)e.z; o1[k+3]=(bf16)e.w; }
    }
    bf16* op = o + (long)row * HID + lane * 16;
    *(bf16x8*)op = o0;
    *(bf16x8*)(op + 8) = o1;
}

// ---------------------------------------------------------------------------
// Local attention: one wave per (token, head). 27 neighbors, zero-padded
// neighbors participate with score exactly 0 (as in reference).
// ---------------------------------------------------------------------------
__global__ __launch_bounds__(256)
void lattn_k(const float* __restrict__ qkv, bf16* __restrict__ ao)
{
    int w    = blockIdx.x * 4 + (threadIdx.x >> 6);
    int lane = threadIdx.x & 63;
    int n = w >> 4, h = w & 15;
    int tt = n >> 8, hh = (n >> 4) & 15, ww = n & 15;

    int nj = -1;
    float dotv = 0.f;
    if (lane < 27) {
        int dt = lane / 9 - 1, dh = (lane % 9) / 3 - 1, dw = lane % 3 - 1;
        int t2 = tt + dt, h2 = hh + dh, w2 = ww + dw;
        if (t2 >= 0 && t2 < 4 && h2 >= 0 && h2 < 16 && w2 >= 0 && w2 < 16)
            nj = (t2 << 8) | (h2 << 4) | w2;
    }
    if (nj >= 0) {
        const f32x4* qp = (const f32x4*)(qkv + (long)n * 3072 + h * 64);
        const f32x4* kp = (const f32x4*)(qkv + (long)nj * 3072 + 1024 + h * 64);
#pragma unroll
        for (int i = 0; i < 16; ++i) {
            f32x4 q4 = qp[i], k4 = kp[i];
            dotv += q4.x * k4.x + q4.y * k4.y + q4.z * k4.z + q4.w * k4.w;
        }
    }
    float sc = (lane < 27) ? dotv * 0.125f : -3.0e38f;
    float mx = sc;
    for (int m = 32; m; m >>= 1) mx = fmaxf(mx, __shfl_xor(mx, m));
    float e = (lane < 27) ? __expf(sc - mx) : 0.f;
    float s = e;
    for (int m = 32; m; m >>= 1) s += __shfl_xor(s, m);
    float p = e / s;

    float acc = 0.f;
    for (int j = 0; j < 27; ++j) {
        float pj = __shfl(p, j);
        int  njj = __shfl(nj, j);
        if (njj >= 0) acc += pj * qkv[(long)njj * 3072 + 2048 + h * 64 + lane];
    }
    ao[(long)n * 1024 + h * 64 + lane] = (bf16)acc;
}

// ---------------------------------------------------------------------------
// Compact masked query indices (1 wave). qidx[0..cnt)=token idx, rest -1.
// ---------------------------------------------------------------------------
__global__ void compact_k(const int* __restrict__ mask, int* __restrict__ qidx)
{
    int lane = threadIdx.x;
    int total = 0;
    for (int base = 0; base < 1024; base += 64) {
        int m = (mask[base + lane] != 0) ? 1 : 0;
        unsigned long long bal = __ballot(m);
        int pos = total + (int)__popcll(bal & ((1ull << lane) - 1ull));
        if (m && pos < QCMAX) qidx[pos] = base + lane;
        total += (int)__popcll(bal);
    }
    for (int i = total + lane; i < QCMAX; i += 64) qidx[i] = -1;
}

// ---------------------------------------------------------------------------
// Build per-head compacted Q, K^T, V in bf16 from f32 qkv.
// Qc[16][256][64], Kt[16][64][1024], Vh[16][1024][64]
// ---------------------------------------------------------------------------
__global__ __launch_bounds__(256)
void build_heads_k(const float* __restrict__ qkv, const int* __restrict__ qidx,
                   bf16* __restrict__ Qc, bf16* __restrict__ Kt, bf16* __restrict__ Vh)
{
    int idx = blockIdx.x * 256 + threadIdx.x;
    if (idx < 262144) {
        int h = idx >> 14, r = (idx >> 6) & 255, d = idx & 63;
        int q = qidx[r];
        float v = (q >= 0) ? qkv[(long)q * 3072 + h * 64 + d] : 0.f;
        Qc[idx] = (bf16)v;
        return;
    }
    int j = idx - 262144;
    if (j < 1048576) {
        int h = j >> 16, d = (j >> 10) & 63, k = j & 1023;
        Kt[j] = (bf16)qkv[(long)k * 3072 + 1024 + h * 64 + d];
        return;
    }
    int j2 = j - 1048576;
    if (j2 < 1048576) {
        int h = j2 >> 16, k = (j2 >> 6) & 1023, d = j2 & 63;
        Vh[j2] = (bf16)qkv[(long)k * 3072 + 2048 + h * 64 + d];
    }
}

// ---------------------------------------------------------------------------
// Row softmax over S[16*256][1024] f32 (pre-scaled by 1/8) -> P bf16.
// ---------------------------------------------------------------------------
__global__ __launch_bounds__(256)
void softmax_k(const float* __restrict__ S, bf16* __restrict__ P)
{
    int row  = blockIdx.x * 4 + (threadIdx.x >> 6);
    int lane = threadIdx.x & 63;
    const f32x4* sp = (const f32x4*)(S + (long)row * 1024) + lane * 4;
    f32x4 v[4];
#pragma unroll
    for (int i = 0; i < 4; ++i) v[i] = sp[i] * 0.125f;
    float mx = -3.0e38f;
#pragma unroll
    for (int i = 0; i < 4; ++i)
        mx = fmaxf(mx, fmaxf(fmaxf(v[i].x, v[i].y), fmaxf(v[i].z, v[i].w)));
    for (int m = 32; m; m >>= 1) mx = fmaxf(mx, __shfl_xor(mx, m));
    f32x4 ev[4];
    float sum = 0.f;
#pragma unroll
    for (int i = 0; i < 4; ++i) {
        ev[i].x = __expf(v[i].x - mx); ev[i].y = __expf(v[i].y - mx);
        ev[i].z = __expf(v[i].z - mx); ev[i].w = __expf(v[i].w - mx);
        sum += ev[i].x + ev[i].y + ev[i].z + ev[i].w;
    }
    for (int m = 32; m; m >>= 1) sum += __shfl_xor(sum, m);
    float inv = 1.f / sum;
    bf16x8 o0, o1;
#pragma unroll
    for (int i = 0; i < 4; ++i) {
        f32x4 e = ev[i] * inv;
        if (i < 2) { o0[i*4+0]=(bf16)e.x; o0[i*4+1]=(bf16)e.y; o0[i*4+2]=(bf16)e.z; o0[i*4+3]=(bf16)e.w; }
        else       { int k=(i-2)*4; o1[k+0]=(bf16)e.x; o1[k+1]=(bf16)e.y; o1[k+2]=(bf16)e.z; o1[k+3]=(bf16)e.w; }
    }
    bf16* op = P + (long)row * 1024 + lane * 16;
    *(bf16x8*)op = o0;
    *(bf16x8*)(op + 8) = o1;
}

// ---------------------------------------------------------------------------
// Prep: patchify + flag + input_proj + pos emb -> x; also store raw tokens.
// One block per 16 tokens.
// ---------------------------------------------------------------------------
__global__ __launch_bounds__(256)
void prep_k(const float* __restrict__ lat, const int* __restrict__ mask,
            const float* __restrict__ Wi, const float* __restrict__ bi,
            const float* __restrict__ et, const float* __restrict__ eh,
            const float* __restrict__ ew,
            float* __restrict__ x, float* __restrict__ tokens)
{
    __shared__ float tl[16][65];
    int t = threadIdx.x;
    int n0 = blockIdx.x * 16;
    for (int idx = t; idx < 16 * 65; idx += 256) {
        int ti = idx / 65, d = idx % 65;
        int n = n0 + ti;
        int tt = n >> 8, hh = (n >> 4) & 15, wwi = n & 15;
        float v;
        if (d < 64) {
            int c = d >> 2, ph = (d >> 1) & 1, pw = d & 1;
            v = lat[(((long)tt * 16 + c) * 32 + hh * 2 + ph) * 32 + wwi * 2 + pw];
            tokens[(long)n * 64 + d] = v;
        } else {
            v = mask[n] ? 1.f : 0.f;
        }
        tl[ti][d] = v;
    }
    __syncthreads();
    f32x4 acc[16];
#pragma unroll
    for (int i = 0; i < 16; ++i) acc[i] = f32x4{0.f, 0.f, 0.f, 0.f};
    for (int d = 0; d < 65; ++d) {
        f32x4 wv = *(const f32x4*)(Wi + (long)d * 1024 + t * 4);
#pragma unroll
        for (int ti = 0; ti < 16; ++ti) acc[ti] += tl[ti][d] * wv;
    }
    f32x4 bb = *(const f32x4*)(bi + t * 4);
    for (int ti = 0; ti < 16; ++ti) {
        int n = n0 + ti;
        int tt = n >> 8, hh = (n >> 4) & 15, wwi = n & 15;
        f32x4 pos = *(const f32x4*)(et + (long)tt * 1024 + t * 4)
                  + *(const f32x4*)(eh + (long)hh * 1024 + t * 4)
                  + *(const f32x4*)(ew + (long)wwi * 1024 + t * 4);
        *(f32x4*)(x + (long)n * 1024 + t * 4) = acc[ti] + bb + pos;
    }
}

// ---------------------------------------------------------------------------
// Final: delta = xn @ out_proj + b; out = unpatchify(tokens + delta).
// One block per 8 tokens.
// ---------------------------------------------------------------------------
__global__ __launch_bounds__(256)
void final_k(const bf16* __restrict__ xn, const float* __restrict__ OW,
             const float* __restrict__ ob, const float* __restrict__ tokens,
             float* __restrict__ out)
{
    __shared__ bf16 xl[8][1024];
    __shared__ float part[4][8][64];
    int t = threadIdx.x;
    int n0 = blockIdx.x * 8;
    for (int i = t; i < 1024; i += 256)
        ((u32x4*)xl)[i] = ((const u32x4*)(xn + (long)n0 * 1024))[i];
    __syncthreads();
    int j = t & 63, s = t >> 6;
    float acc[8] = {0.f, 0.f, 0.f, 0.f, 0.f, 0.f, 0.f, 0.f};
    for (int k = s * 256; k < s * 256 + 256; ++k) {
        float w = OW[(long)k * 64 + j];
#pragma unroll
        for (int ti = 0; ti < 8; ++ti) acc[ti] += (float)xl[ti][k] * w;
    }
    for (int ti = 0; ti < 8; ++ti) part[s][ti][j] = acc[ti];
    __syncthreads();
    if (s == 0) {
        for (int ti = 0; ti < 8; ++ti) {
            int n = n0 + ti;
            float v = part[0][ti][j] + part[1][ti][j] + part[2][ti][j] + part[3][ti][j]
                    + ob[j] + tokens[(long)n * 64 + j];
            int tt = n >> 8, hh = (n >> 4) & 15, wwi = n & 15;
            int c = j >> 2, ph = (j >> 1) & 1, pw = j & 1;
            out[(((long)tt * 16 + c) * 32 + hh * 2 + ph) * 32 + wwi * 2 + pw] = v;
        }
    }
}

// ---------------------------------------------------------------------------
extern "C" void kernel_launch(void* const* d_in, const int* in_sizes, int n_in,
                              void* d_out, int out_size, void* d_ws, size_t ws_size,
                              hipStream_t stream)
{
    const float* latents = (const float*)d_in[0];
    const int*   mask    = (const int*)d_in[1];
    const float* ipw  = (const float*)d_in[2];
    const float* ipb  = (const float*)d_in[3];
    const float* et   = (const float*)d_in[4];
    const float* eh   = (const float*)d_in[5];
    const float* ew   = (const float*)d_in[6];
    const float* lnlw = (const float*)d_in[7];
    const float* lnlb = (const float*)d_in[8];
    const float* lngw = (const float*)d_in[9];
    const float* lngb = (const float*)d_in[10];
    const float* lnfw = (const float*)d_in[11];
    const float* lnfb = (const float*)d_in[12];
    const float* lqkv = (const float*)d_in[13];
    const float* lout = (const float*)d_in[14];
    const float* gqkv = (const float*)d_in[15];
    const float* gout = (const float*)d_in[16];
    const float* w1   = (const float*)d_in[17];
    const float* b1   = (const float*)d_in[18];
    const float* w2   = (const float*)d_in[19];
    const float* b2   = (const float*)d_in[20];
    const float* flw  = (const float*)d_in[21];
    const float* flb  = (const float*)d_in[22];
    const float* opw  = (const float*)d_in[23];
    const float* opb  = (const float*)d_in[24];

    char* p = (char*)d_ws;
    auto alloc = [&](size_t bytes) { char* r = p; p += (bytes + 255) & ~(size_t)255; return r; };
    float* x      = (float*)alloc((size_t)4 << 20);
    bf16*  xn     = (bf16*)alloc((size_t)2 << 20);
    float* qkv    = (float*)alloc((size_t)12 << 20);
    bf16*  ao     = (bf16*)alloc((size_t)2 << 20);
    bf16*  hbuf   = (bf16*)alloc((size_t)8 << 20);
    float* tokens = (float*)alloc((size_t)256 << 10);
    bf16*  Qc     = (bf16*)alloc((size_t)512 << 10);
    bf16*  Kt     = (bf16*)alloc((size_t)2 << 20);
    bf16*  Vh     = (bf16*)alloc((size_t)2 << 20);
    float* S      = (float*)alloc((size_t)16 << 20);
    bf16*  P      = (bf16*)alloc((size_t)8 << 20);
    bf16*  Oc     = (bf16*)alloc((size_t)512 << 10);
    int*   qidx   = (int*)alloc(4096);

    prep_k<<<64, 256, 0, stream>>>(latents, mask, ipw, ipb, et, eh, ew, x, tokens);
    compact_k<<<1, 64, 0, stream>>>(mask, qidx);

    for (int l = 0; l < NL; ++l) {
        // ---- local attention block ----
        ln_k<<<256, 256, 0, stream>>>(x, lnlw + l * HID, lnlb + l * HID, xn);
        gemm_k<EPI_F32, true><<<dim3(24, 8, 1), 256, 0, stream>>>(
            xn, 1024, 0, lqkv + (long)l * 1024 * 3072, 3072, 0,
            qkv, 3072, 0, nullptr, nullptr, 1024, 3072, 1024);
        lattn_k<<<4096, 256, 0, stream>>>(qkv, ao);
        gemm_k<EPI_RESID, true><<<dim3(8, 8, 1), 256, 0, stream>>>(
            ao, 1024, 0, lout + (long)l * 1024 * 1024, 1024, 0,
            x, 1024, 0, nullptr, nullptr, 1024, 1024, 1024);
        // ---- global attention block (masked queries only) ----
        ln_k<<<256, 256, 0, stream>>>(x, lngw + l * HID, lngb + l * HID, xn);
        gemm_k<EPI_F32, true><<<dim3(24, 8, 1), 256, 0, stream>>>(
            xn, 1024, 0, gqkv + (long)l * 1024 * 3072, 3072, 0,
            qkv, 3072, 0, nullptr, nullptr, 1024, 3072, 1024);
        build_heads_k<<<9216, 256, 0, stream>>>(qkv, qidx, Qc, Kt, Vh);
        gemm_k<EPI_F32, false><<<dim3(8, 2, 16), 256, 0, stream>>>(
            Qc, 64, (long)256 * 64, Kt, 1024, (long)64 * 1024,
            S, 1024, (long)256 * 1024, nullptr, nullptr, 256, 1024, 64);
        softmax_k<<<1024, 256, 0, stream>>>(S, P);
        gemm_k<EPI_BF16, false><<<dim3(1, 2, 16), 256, 0, stream>>>(
            P, 1024, (long)256 * 1024, Vh, 64, (long)1024 * 64,
            Oc, 1024, 64, nullptr, nullptr, 256, 64, 1024);
        gemm_k<EPI_SCATTER, true><<<dim3(8, 2, 1), 256, 0, stream>>>(
            Oc, 1024, 0, gout + (long)l * 1024 * 1024, 1024, 0,
            x, 1024, 0, nullptr, qidx, 256, 1024, 1024);
        // ---- FFN ----
        ln_k<<<256, 256, 0, stream>>>(x, lnfw + l * HID, lnfb + l * HID, xn);
        gemm_k<EPI_GELU, true><<<dim3(32, 8, 1), 256, 0, stream>>>(
            xn, 1024, 0, w1 + (long)l * 1024 * 4096, 4096, 0,
            hbuf, 4096, 0, b1 + l * 4096, nullptr, 1024, 4096, 1024);
        gemm_k<EPI_BIAS_RESID, true><<<dim3(8, 8, 1), 256, 0, stream>>>(
            hbuf, 4096, 0, w2 + (long)l * 4096 * 1024, 1024, 0,
            x, 1024, 0, b2 + l * 1024, nullptr, 1024, 1024, 4096);
    }

    ln_k<<<256, 256, 0, stream>>>(x, flw, flb, xn);
    final_k<<<128, 256, 0, stream>>>(xn, opw, opb, tokens, (float*)d_out);
}

// Round 2
// 3419.653 us; speedup vs baseline: 1.6026x; 1.6026x over previous
//
#include <hip/hip_runtime.h>
#include <hip/hip_bf16.h>
#include <math.h>

typedef __bf16 bf16;
typedef __bf16 bf16x8 __attribute__((ext_vector_type(8)));
typedef float  f32x4 __attribute__((ext_vector_type(4)));
typedef unsigned int u32x4 __attribute__((ext_vector_type(4)));

#define NTOK 1024
#define HID  1024
#define NH   16
#define HD   64
#define NL   10
#define QCMAX 256

#define EPI_F32        0
#define EPI_BF16       1
#define EPI_RESID      2
#define EPI_SCATTER    3
#define EPI_GELU       4
#define EPI_BIAS_RESID 5

// ---------------------------------------------------------------------------
// Weight convert+transpose: W[K][N] f32 -> Wt[N][K] bf16.  64x64 LDS tile.
// grid (N/64, K/64, layers)
// ---------------------------------------------------------------------------
__global__ __launch_bounds__(256)
void wtrans_k(const float* __restrict__ W, bf16* __restrict__ Wt, int K, int N)
{
    __shared__ bf16 tile[64][72];
    const long mofs = (long)blockIdx.z * K * N;
    const float* Ws = W + mofs;
    bf16* Wo = Wt + mofs;
    const int n0 = blockIdx.x * 64, k0 = blockIdx.y * 64;
    const int t = threadIdx.x;
    {
        const int r = t >> 2, cc = (t & 3) * 16;
        const float* src = Ws + (long)(k0 + r) * N + n0 + cc;
#pragma unroll
        for (int i = 0; i < 2; ++i) {
            f32x4 a = *(const f32x4*)(src + i * 8);
            f32x4 b = *(const f32x4*)(src + i * 8 + 4);
            bf16x8 w;
            w[0]=(bf16)a.x; w[1]=(bf16)a.y; w[2]=(bf16)a.z; w[3]=(bf16)a.w;
            w[4]=(bf16)b.x; w[5]=(bf16)b.y; w[6]=(bf16)b.z; w[7]=(bf16)b.w;
            *(bf16x8*)&tile[r][cc + i * 8] = w;
        }
    }
    __syncthreads();
    {
        const int n = t >> 2, kc = (t & 3) * 16;
        bf16x8 o0, o1;
#pragma unroll
        for (int j = 0; j < 8; ++j) { o0[j] = tile[kc + j][n]; o1[j] = tile[kc + 8 + j][n]; }
        bf16* dst = Wo + (long)(n0 + n) * K + k0 + kc;
        *(bf16x8*)dst = o0;
        *(bf16x8*)(dst + 8) = o1;
    }
}

// ---------------------------------------------------------------------------
// m97-style GEMM: C[M,N] (+)= A[M,K] * Bt[N,K]^T, both bf16 row-major-over-K.
// BK=32, 256 threads. BM/BN in {64,128}; all problem dims divide evenly.
// ---------------------------------------------------------------------------
template<int EPI, int BM, int BN>
__global__ __launch_bounds__(256)
void gemm_k(const bf16* __restrict__ A, int lda, long bsA,
            const bf16* __restrict__ Bt, int ldb, long bsB,
            void* __restrict__ Cv, int ldc, long bsC,
            const float* __restrict__ bias,
            const int* __restrict__ qidx,
            int K)
{
    constexpr int WC  = (BM == 128) ? 2 : 4;   // wave grid cols
    constexpr int WTN = BN / WC;               // wave tile N
    constexpr int NF  = WTN / 16;              // N fragments per wave
    __shared__ bf16 Al[BM * 32];
    __shared__ bf16 Bl[BN * 32];

    const int t    = threadIdx.x;
    const int lane = t & 63;
    const int wv   = t >> 6;
    const int wr   = wv / WC, wc = wv % WC;
    const int lrow = lane & 15, lk = lane >> 4;
    const int n0   = blockIdx.x * BN;
    const int m0   = blockIdx.y * BM;
    const bf16* Ab = A + bsA * blockIdx.z;
    const bf16* Bb = Bt + bsB * blockIdx.z;

    f32x4 acc[4][NF];
#pragma unroll
    for (int m = 0; m < 4; ++m)
#pragma unroll
        for (int n = 0; n < NF; ++n) acc[m][n] = f32x4{0.f, 0.f, 0.f, 0.f};

    const int sr = t >> 2, sc = (t & 3) * 8;

    for (int k0 = 0; k0 < K; k0 += 32) {
#pragma unroll
        for (int i = 0; i < BM / 64; ++i)
            __builtin_amdgcn_global_load_lds(
                (const __attribute__((address_space(1))) void*)(Ab + (long)(m0 + sr + i * 64) * lda + k0 + sc),
                (__attribute__((address_space(3))) void*)(&Al[i * 2048 + t * 8]), 16, 0, 0);
#pragma unroll
        for (int i = 0; i < BN / 64; ++i)
            __builtin_amdgcn_global_load_lds(
                (const __attribute__((address_space(1))) void*)(Bb + (long)(n0 + sr + i * 64) * ldb + k0 + sc),
                (__attribute__((address_space(3))) void*)(&Bl[i * 2048 + t * 8]), 16, 0, 0);
        __syncthreads();

        bf16x8 af[4], bfv[NF];
#pragma unroll
        for (int m = 0; m < 4; ++m)
            af[m] = *(const bf16x8*)&Al[(wr * 64 + m * 16 + lrow) * 32 + lk * 8];
#pragma unroll
        for (int n = 0; n < NF; ++n)
            bfv[n] = *(const bf16x8*)&Bl[(wc * WTN + n * 16 + lrow) * 32 + lk * 8];
#pragma unroll
        for (int m = 0; m < 4; ++m)
#pragma unroll
            for (int n = 0; n < NF; ++n)
                acc[m][n] = __builtin_amdgcn_mfma_f32_16x16x32_bf16(af[m], bfv[n], acc[m][n], 0, 0, 0);
        __syncthreads();
    }

    float* Cf = (float*)Cv + bsC * blockIdx.z;
    bf16*  Cb = (bf16*)Cv + bsC * blockIdx.z;
#pragma unroll
    for (int m = 0; m < 4; ++m) {
#pragma unroll
        for (int n = 0; n < NF; ++n) {
            const int c = n0 + wc * WTN + n * 16 + lrow;
#pragma unroll
            for (int q = 0; q < 4; ++q) {
                const int r = m0 + wr * 64 + m * 16 + lk * 4 + q;
                const float v = acc[m][n][q];
                const long off = (long)r * ldc + c;
                if (EPI == EPI_F32)        Cf[off] = v;
                else if (EPI == EPI_BF16)  Cb[off] = (bf16)v;
                else if (EPI == EPI_RESID) Cf[off] += v;
                else if (EPI == EPI_SCATTER) {
                    int rr = qidx[r];
                    if (rr >= 0) Cf[(long)rr * ldc + c] += v;
                } else if (EPI == EPI_GELU) {
                    float u = v + bias[c];
                    Cb[off] = (bf16)(0.5f * u * (1.f + erff(u * 0.70710678118654752f)));
                } else if (EPI == EPI_BIAS_RESID) {
                    Cf[off] += v + bias[c];
                }
            }
        }
    }
}

// ---------------------------------------------------------------------------
// LayerNorm rows of 1024 f32 -> bf16. One wave per row.
// ---------------------------------------------------------------------------
__global__ __launch_bounds__(256)
void ln_k(const float* __restrict__ x, const float* __restrict__ w,
          const float* __restrict__ b, bf16* __restrict__ o)
{
    int row  = blockIdx.x * 4 + (threadIdx.x >> 6);
    int lane = threadIdx.x & 63;
    const f32x4* xr = (const f32x4*)(x + (long)row * HID) + lane * 4;
    f32x4 v[4];
#pragma unroll
    for (int i = 0; i < 4; ++i) v[i] = xr[i];
    float s = 0.f;
#pragma unroll
    for (int i = 0; i < 4; ++i) s += v[i].x + v[i].y + v[i].z + v[i].w;
    for (int m = 32; m; m >>= 1) s += __shfl_xor(s, m);
    float mean = s * (1.f / 1024.f);
    f32x4 d[4];
    float ss = 0.f;
#pragma unroll
    for (int i = 0; i < 4; ++i) {
        d[i] = v[i] - mean;
        ss += d[i].x * d[i].x + d[i].y * d[i].y + d[i].z * d[i].z + d[i].w * d[i].w;
    }
    for (int m = 32; m; m >>= 1) ss += __shfl_xor(ss, m);
    float rs = rsqrtf(ss * (1.f / 1024.f) + 1e-5f);
    const f32x4* wp = (const f32x4*)w + lane * 4;
    const f32x4* bp = (const f32x4*)b + lane * 4;
    bf16x8 o0, o1;
#pragma unroll
    for (int i = 0; i < 4; ++i) {
        f32x4 wv = wp[i], bv = bp[i];
        f32x4 e;
        e.x = d[i].x * rs * wv.x + bv.x; e.y = d[i].y * rs * wv.y + bv.y;
        e.z = d[i].z * rs * wv.z + bv.z; e.w = d[i].w * rs * wv.w + bv.w;
        if (i < 2) { o0[i*4+0]=(bf16)e.x; o0[i*4+1]=(bf16)e.y; o0[i*4+2]=(bf16)e.z; o0[i*4+3]=(bf16)e.w; }
        else       { int k=(i-2)*4; o1[k+0]=(bf16)e.x; o1[k+1]=(bf16)e.y; o1[k+2]=(bf16)e.z; o1[k+3]=(bf16)e.w; }
    }
    bf16* op = o + (long)row * HID + lane * 16;
    *(bf16x8*)op = o0;
    *(bf16x8*)(op + 8) = o1;
}

// ---------------------------------------------------------------------------
// Local attention: one wave per (token, head); zero-padded neighbors keep
// score exactly 0 in the softmax (reference semantics).
// ---------------------------------------------------------------------------
__global__ __launch_bounds__(256)
void lattn_k(const float* __restrict__ qkv, bf16* __restrict__ ao)
{
    int w    = blockIdx.x * 4 + (threadIdx.x >> 6);
    int lane = threadIdx.x & 63;
    int n = w >> 4, h = w & 15;
    int tt = n >> 8, hh = (n >> 4) & 15, ww = n & 15;

    int nj = -1;
    float dotv = 0.f;
    if (lane < 27) {
        int dt = lane / 9 - 1, dh = (lane % 9) / 3 - 1, dw = lane % 3 - 1;
        int t2 = tt + dt, h2 = hh + dh, w2 = ww + dw;
        if (t2 >= 0 && t2 < 4 && h2 >= 0 && h2 < 16 && w2 >= 0 && w2 < 16)
            nj = (t2 << 8) | (h2 << 4) | w2;
    }
    if (nj >= 0) {
        const f32x4* qp = (const f32x4*)(qkv + (long)n * 3072 + h * 64);
        const f32x4* kp = (const f32x4*)(qkv + (long)nj * 3072 + 1024 + h * 64);
#pragma unroll
        for (int i = 0; i < 16; ++i) {
            f32x4 q4 = qp[i], k4 = kp[i];
            dotv += q4.x * k4.x + q4.y * k4.y + q4.z * k4.z + q4.w * k4.w;
        }
    }
    float sc = (lane < 27) ? dotv * 0.125f : -3.0e38f;
    float mx = sc;
    for (int m = 32; m; m >>= 1) mx = fmaxf(mx, __shfl_xor(mx, m));
    float e = (lane < 27) ? __expf(sc - mx) : 0.f;
    float s = e;
    for (int m = 32; m; m >>= 1) s += __shfl_xor(s, m);
    float p = e / s;

    float acc = 0.f;
    for (int j = 0; j < 27; ++j) {
        float pj = __shfl(p, j);
        int  njj = __shfl(nj, j);
        if (njj >= 0) acc += pj * qkv[(long)njj * 3072 + 2048 + h * 64 + lane];
    }
    ao[(long)n * 1024 + h * 64 + lane] = (bf16)acc;
}

// ---------------------------------------------------------------------------
__global__ void compact_k(const int* __restrict__ mask, int* __restrict__ qidx)
{
    int lane = threadIdx.x;
    int total = 0;
    for (int base = 0; base < 1024; base += 64) {
        int m = (mask[base + lane] != 0) ? 1 : 0;
        unsigned long long bal = __ballot(m);
        int pos = total + (int)__popcll(bal & ((1ull << lane) - 1ull));
        if (m && pos < QCMAX) qidx[pos] = base + lane;
        total += (int)__popcll(bal);
    }
    for (int i = total + lane; i < QCMAX; i += 64) qidx[i] = -1;
}

// ---------------------------------------------------------------------------
// Qc[h][r][d] = 0.125 * qkv[qidx[r]][q, h, d]  (zeros for r without query)
// grid (4 row-tiles, 16 heads)
// ---------------------------------------------------------------------------
__global__ __launch_bounds__(256)
void qbuild_k(const float* __restrict__ qkv, const int* __restrict__ qidx,
              bf16* __restrict__ Qc)
{
    const int h = blockIdx.y;
    const int t = threadIdx.x;
    const int r = blockIdx.x * 64 + (t >> 2), dc = (t & 3) * 16;
    const int q = qidx[r];
    bf16x8 o0, o1;
    if (q >= 0) {
        const f32x4* src = (const f32x4*)(qkv + (long)q * 3072 + h * 64 + dc);
#pragma unroll
        for (int i = 0; i < 2; ++i) {
            f32x4 a = src[i * 2] * 0.125f, b = src[i * 2 + 1] * 0.125f;
            bf16x8 w;
            w[0]=(bf16)a.x; w[1]=(bf16)a.y; w[2]=(bf16)a.z; w[3]=(bf16)a.w;
            w[4]=(bf16)b.x; w[5]=(bf16)b.y; w[6]=(bf16)b.z; w[7]=(bf16)b.w;
            if (i == 0) o0 = w; else o1 = w;
        }
    } else {
#pragma unroll
        for (int j = 0; j < 8; ++j) { o0[j] = (bf16)0.f; o1[j] = (bf16)0.f; }
    }
    bf16* dst = Qc + (long)h * (QCMAX * 64) + (long)r * 64 + dc;
    *(bf16x8*)dst = o0;
    *(bf16x8*)(dst + 8) = o1;
}

// ---------------------------------------------------------------------------
// Kh[h][tok][d] and Vt[h][d][tok] from f32 qkv.  grid (16 tok-tiles, 16 heads)
// ---------------------------------------------------------------------------
__global__ __launch_bounds__(256)
void kvbuild_k(const float* __restrict__ qkv, bf16* __restrict__ Kh,
               bf16* __restrict__ Vt)
{
    __shared__ bf16 vt[64][72];
    const int h = blockIdx.y;
    const int k0 = blockIdx.x * 64;
    const int t = threadIdx.x;
    {
        const int r = t >> 2, dc = (t & 3) * 16;
        const float* kp = qkv + (long)(k0 + r) * 3072 + 1024 + h * 64 + dc;
        const float* vp = kp + 1024;
        bf16x8 ko0, ko1;
#pragma unroll
        for (int i = 0; i < 2; ++i) {
            f32x4 a = *(const f32x4*)(kp + i * 8);
            f32x4 b = *(const f32x4*)(kp + i * 8 + 4);
            bf16x8 w;
            w[0]=(bf16)a.x; w[1]=(bf16)a.y; w[2]=(bf16)a.z; w[3]=(bf16)a.w;
            w[4]=(bf16)b.x; w[5]=(bf16)b.y; w[6]=(bf16)b.z; w[7]=(bf16)b.w;
            if (i == 0) ko0 = w; else ko1 = w;
        }
        bf16* kd = Kh + (long)h * (NTOK * 64) + (long)(k0 + r) * 64 + dc;
        *(bf16x8*)kd = ko0;
        *(bf16x8*)(kd + 8) = ko1;
#pragma unroll
        for (int i = 0; i < 2; ++i) {
            f32x4 a = *(const f32x4*)(vp + i * 8);
            f32x4 b = *(const f32x4*)(vp + i * 8 + 4);
            bf16x8 w;
            w[0]=(bf16)a.x; w[1]=(bf16)a.y; w[2]=(bf16)a.z; w[3]=(bf16)a.w;
            w[4]=(bf16)b.x; w[5]=(bf16)b.y; w[6]=(bf16)b.z; w[7]=(bf16)b.w;
            *(bf16x8*)&vt[r][dc + i * 8] = w;
        }
    }
    __syncthreads();
    {
        const int d = t >> 2, kc = (t & 3) * 16;
        bf16x8 o0, o1;
#pragma unroll
        for (int j = 0; j < 8; ++j) { o0[j] = vt[kc + j][d]; o1[j] = vt[kc + 8 + j][d]; }
        bf16* dst = Vt + (long)h * (64 * NTOK) + (long)d * NTOK + k0 + kc;
        *(bf16x8*)dst = o0;
        *(bf16x8*)(dst + 8) = o1;
    }
}

// ---------------------------------------------------------------------------
// Row softmax over S[16*256][1024] f32 (already scaled) -> P bf16.
// ---------------------------------------------------------------------------
__global__ __launch_bounds__(256)
void softmax_k(const float* __restrict__ S, bf16* __restrict__ P)
{
    int row  = blockIdx.x * 4 + (threadIdx.x >> 6);
    int lane = threadIdx.x & 63;
    const f32x4* sp = (const f32x4*)(S + (long)row * 1024) + lane * 4;
    f32x4 v[4];
#pragma unroll
    for (int i = 0; i < 4; ++i) v[i] = sp[i];
    float mx = -3.0e38f;
#pragma unroll
    for (int i = 0; i < 4; ++i)
        mx = fmaxf(mx, fmaxf(fmaxf(v[i].x, v[i].y), fmaxf(v[i].z, v[i].w)));
    for (int m = 32; m; m >>= 1) mx = fmaxf(mx, __shfl_xor(mx, m));
    f32x4 ev[4];
    float sum = 0.f;
#pragma unroll
    for (int i = 0; i < 4; ++i) {
        ev[i].x = __expf(v[i].x - mx); ev[i].y = __expf(v[i].y - mx);
        ev[i].z = __expf(v[i].z - mx); ev[i].w = __expf(v[i].w - mx);
        sum += ev[i].x + ev[i].y + ev[i].z + ev[i].w;
    }
    for (int m = 32; m; m >>= 1) sum += __shfl_xor(sum, m);
    float inv = 1.f / sum;
    bf16x8 o0, o1;
#pragma unroll
    for (int i = 0; i < 4; ++i) {
        f32x4 e = ev[i] * inv;
        if (i < 2) { o0[i*4+0]=(bf16)e.x; o0[i*4+1]=(bf16)e.y; o0[i*4+2]=(bf16)e.z; o0[i*4+3]=(bf16)e.w; }
        else       { int k=(i-2)*4; o1[k+0]=(bf16)e.x; o1[k+1]=(bf16)e.y; o1[k+2]=(bf16)e.z; o1[k+3]=(bf16)e.w; }
    }
    bf16* op = P + (long)row * 1024 + lane * 16;
    *(bf16x8*)op = o0;
    *(bf16x8*)(op + 8) = o1;
}

// ---------------------------------------------------------------------------
__global__ __launch_bounds__(256)
void prep_k(const float* __restrict__ lat, const int* __restrict__ mask,
            const float* __restrict__ Wi, const float* __restrict__ bi,
            const float* __restrict__ et, const float* __restrict__ eh,
            const float* __restrict__ ew,
            float* __restrict__ x, float* __restrict__ tokens)
{
    __shared__ float tl[16][65];
    int t = threadIdx.x;
    int n0 = blockIdx.x * 16;
    for (int idx = t; idx < 16 * 65; idx += 256) {
        int ti = idx / 65, d = idx % 65;
        int n = n0 + ti;
        int tt = n >> 8, hh = (n >> 4) & 15, wwi = n & 15;
        float v;
        if (d < 64) {
            int c = d >> 2, ph = (d >> 1) & 1, pw = d & 1;
            v = lat[(((long)tt * 16 + c) * 32 + hh * 2 + ph) * 32 + wwi * 2 + pw];
            tokens[(long)n * 64 + d] = v;
        } else {
            v = mask[n] ? 1.f : 0.f;
        }
        tl[ti][d] = v;
    }
    __syncthreads();
    f32x4 acc[16];
#pragma unroll
    for (int i = 0; i < 16; ++i) acc[i] = f32x4{0.f, 0.f, 0.f, 0.f};
    for (int d = 0; d < 65; ++d) {
        f32x4 wv = *(const f32x4*)(Wi + (long)d * 1024 + t * 4);
#pragma unroll
        for (int ti = 0; ti < 16; ++ti) acc[ti] += tl[ti][d] * wv;
    }
    f32x4 bb = *(const f32x4*)(bi + t * 4);
    for (int ti = 0; ti < 16; ++ti) {
        int n = n0 + ti;
        int tt = n >> 8, hh = (n >> 4) & 15, wwi = n & 15;
        f32x4 pos = *(const f32x4*)(et + (long)tt * 1024 + t * 4)
                  + *(const f32x4*)(eh + (long)hh * 1024 + t * 4)
                  + *(const f32x4*)(ew + (long)wwi * 1024 + t * 4);
        *(f32x4*)(x + (long)n * 1024 + t * 4) = acc[ti] + bb + pos;
    }
}

// ---------------------------------------------------------------------------
__global__ __launch_bounds__(256)
void final_k(const bf16* __restrict__ xn, const float* __restrict__ OW,
             const float* __restrict__ ob, const float* __restrict__ tokens,
             float* __restrict__ out)
{
    __shared__ bf16 xl[8][1024];
    __shared__ float part[4][8][64];
    int t = threadIdx.x;
    int n0 = blockIdx.x * 8;
    for (int i = t; i < 1024; i += 256)
        ((u32x4*)xl)[i] = ((const u32x4*)(xn + (long)n0 * 1024))[i];
    __syncthreads();
    int j = t & 63, s = t >> 6;
    float acc[8] = {0.f, 0.f, 0.f, 0.f, 0.f, 0.f, 0.f, 0.f};
    for (int k = s * 256; k < s * 256 + 256; ++k) {
        float w = OW[(long)k * 64 + j];
#pragma unroll
        for (int ti = 0; ti < 8; ++ti) acc[ti] += (float)xl[ti][k] * w;
    }
    for (int ti = 0; ti < 8; ++ti) part[s][ti][j] = acc[ti];
    __syncthreads();
    if (s == 0) {
        for (int ti = 0; ti < 8; ++ti) {
            int n = n0 + ti;
            float v = part[0][ti][j] + part[1][ti][j] + part[2][ti][j] + part[3][ti][j]
                    + ob[j] + tokens[(long)n * 64 + j];
            int tt = n >> 8, hh = (n >> 4) & 15, wwi = n & 15;
            int c = j >> 2, ph = (j >> 1) & 1, pw = j & 1;
            out[(((long)tt * 16 + c) * 32 + hh * 2 + ph) * 32 + wwi * 2 + pw] = v;
        }
    }
}

// ---------------------------------------------------------------------------
extern "C" void kernel_launch(void* const* d_in, const int* in_sizes, int n_in,
                              void* d_out, int out_size, void* d_ws, size_t ws_size,
                              hipStream_t stream)
{
    const float* latents = (const float*)d_in[0];
    const int*   mask    = (const int*)d_in[1];
    const float* ipw  = (const float*)d_in[2];
    const float* ipb  = (const float*)d_in[3];
    const float* et   = (const float*)d_in[4];
    const float* eh   = (const float*)d_in[5];
    const float* ew   = (const float*)d_in[6];
    const float* lnlw = (const float*)d_in[7];
    const float* lnlb = (const float*)d_in[8];
    const float* lngw = (const float*)d_in[9];
    const float* lngb = (const float*)d_in[10];
    const float* lnfw = (const float*)d_in[11];
    const float* lnfb = (const float*)d_in[12];
    const float* lqkv = (const float*)d_in[13];
    const float* lout = (const float*)d_in[14];
    const float* gqkv = (const float*)d_in[15];
    const float* gout = (const float*)d_in[16];
    const float* w1   = (const float*)d_in[17];
    const float* b1   = (const float*)d_in[18];
    const float* w2   = (const float*)d_in[19];
    const float* b2   = (const float*)d_in[20];
    const float* flw  = (const float*)d_in[21];
    const float* flb  = (const float*)d_in[22];
    const float* opw  = (const float*)d_in[23];
    const float* opb  = (const float*)d_in[24];

    char* p = (char*)d_ws;
    auto alloc = [&](size_t bytes) { char* r = p; p += (bytes + 255) & ~(size_t)255; return r; };
    // activations / attention scratch
    float* x      = (float*)alloc((size_t)4 << 20);
    bf16*  xn     = (bf16*)alloc((size_t)2 << 20);
    float* qkv    = (float*)alloc((size_t)12 << 20);
    bf16*  ao     = (bf16*)alloc((size_t)2 << 20);
    bf16*  hbuf   = (bf16*)alloc((size_t)8 << 20);
    float* tokens = (float*)alloc((size_t)256 << 10);
    bf16*  Qc     = (bf16*)alloc((size_t)512 << 10);
    bf16*  Kh     = (bf16*)alloc((size_t)2 << 20);
    bf16*  Vt     = (bf16*)alloc((size_t)2 << 20);
    float* S      = (float*)alloc((size_t)16 << 20);
    bf16*  P      = (bf16*)alloc((size_t)8 << 20);
    bf16*  Oc     = (bf16*)alloc((size_t)512 << 10);
    int*   qidx   = (int*)alloc(4096);
    // bf16 transposed weights: Wt[N][K] per layer
    bf16* lqkvT = (bf16*)alloc((size_t)10 * 3072 * 1024 * 2);
    bf16* loutT = (bf16*)alloc((size_t)10 * 1024 * 1024 * 2);
    bf16* gqkvT = (bf16*)alloc((size_t)10 * 3072 * 1024 * 2);
    bf16* goutT = (bf16*)alloc((size_t)10 * 1024 * 1024 * 2);
    bf16* w1T   = (bf16*)alloc((size_t)10 * 4096 * 1024 * 2);
    bf16* w2T   = (bf16*)alloc((size_t)10 * 1024 * 4096 * 2);

    // ---- one-time per call: convert + transpose weights to bf16 ----
    wtrans_k<<<dim3(48, 16, NL), 256, 0, stream>>>(lqkv, lqkvT, 1024, 3072);
    wtrans_k<<<dim3(16, 16, NL), 256, 0, stream>>>(lout, loutT, 1024, 1024);
    wtrans_k<<<dim3(48, 16, NL), 256, 0, stream>>>(gqkv, gqkvT, 1024, 3072);
    wtrans_k<<<dim3(16, 16, NL), 256, 0, stream>>>(gout, goutT, 1024, 1024);
    wtrans_k<<<dim3(64, 16, NL), 256, 0, stream>>>(w1, w1T, 1024, 4096);
    wtrans_k<<<dim3(16, 64, NL), 256, 0, stream>>>(w2, w2T, 4096, 1024);

    prep_k<<<64, 256, 0, stream>>>(latents, mask, ipw, ipb, et, eh, ew, x, tokens);
    compact_k<<<1, 64, 0, stream>>>(mask, qidx);

    for (int l = 0; l < NL; ++l) {
        const long wq = (long)l * 3072 * 1024;
        const long wo = (long)l * 1024 * 1024;
        const long wf1 = (long)l * 4096 * 1024;
        // ---- local attention ----
        ln_k<<<256, 256, 0, stream>>>(x, lnlw + l * HID, lnlb + l * HID, xn);
        gemm_k<EPI_F32, 128, 128><<<dim3(24, 8, 1), 256, 0, stream>>>(
            xn, 1024, 0, lqkvT + wq, 1024, 0,
            qkv, 3072, 0, nullptr, nullptr, 1024);
        lattn_k<<<4096, 256, 0, stream>>>(qkv, ao);
        gemm_k<EPI_RESID, 64, 128><<<dim3(8, 16, 1), 256, 0, stream>>>(
            ao, 1024, 0, loutT + wo, 1024, 0,
            x, 1024, 0, nullptr, nullptr, 1024);
        // ---- global attention (masked queries) ----
        ln_k<<<256, 256, 0, stream>>>(x, lngw + l * HID, lngb + l * HID, xn);
        gemm_k<EPI_F32, 128, 128><<<dim3(24, 8, 1), 256, 0, stream>>>(
            xn, 1024, 0, gqkvT + wq, 1024, 0,
            qkv, 3072, 0, nullptr, nullptr, 1024);
        qbuild_k<<<dim3(4, 16), 256, 0, stream>>>(qkv, qidx, Qc);
        kvbuild_k<<<dim3(16, 16), 256, 0, stream>>>(qkv, Kh, Vt);
        gemm_k<EPI_F32, 64, 128><<<dim3(8, 4, 16), 256, 0, stream>>>(
            Qc, 64, (long)256 * 64, Kh, 64, (long)1024 * 64,
            S, 1024, (long)256 * 1024, nullptr, nullptr, 64);
        softmax_k<<<1024, 256, 0, stream>>>(S, P);
        gemm_k<EPI_BF16, 64, 64><<<dim3(1, 4, 16), 256, 0, stream>>>(
            P, 1024, (long)256 * 1024, Vt, 1024, (long)64 * 1024,
            Oc, 1024, 64, nullptr, nullptr, 1024);
        gemm_k<EPI_SCATTER, 64, 128><<<dim3(8, 4, 1), 256, 0, stream>>>(
            Oc, 1024, 0, goutT + wo, 1024, 0,
            x, 1024, 0, nullptr, qidx, 1024);
        // ---- FFN ----
        ln_k<<<256, 256, 0, stream>>>(x, lnfw + l * HID, lnfb + l * HID, xn);
        gemm_k<EPI_GELU, 128, 128><<<dim3(32, 8, 1), 256, 0, stream>>>(
            xn, 1024, 0, w1T + wf1, 1024, 0,
            hbuf, 4096, 0, b1 + l * 4096, nullptr, 1024);
        gemm_k<EPI_BIAS_RESID, 64, 128><<<dim3(8, 16, 1), 256, 0, stream>>>(
            hbuf, 4096, 0, w2T + wf1, 4096, 0,
            x, 1024, 0, b2 + l * 1024, nullptr, 4096);
    }

    ln_k<<<256, 256, 0, stream>>>(x, flw, flb, xn);
    final_k<<<128, 256, 0, stream>>>(xn, opw, opb, tokens, (float*)d_out);
}

// Round 3
// 2300.206 us; speedup vs baseline: 2.3825x; 1.4867x over previous
//
#include <hip/hip_runtime.h>
#include <hip/hip_bf16.h>
#include <math.h>

typedef __bf16 bf16;
typedef __bf16 bf16x8 __attribute__((ext_vector_type(8)));
typedef __bf16 bf16x4 __attribute__((ext_vector_type(4)));
typedef float  f32x4 __attribute__((ext_vector_type(4)));
typedef unsigned int u32x4 __attribute__((ext_vector_type(4)));

#define NTOK 1024
#define HID  1024
#define NH   16
#define HD   64
#define NL   10
#define QCMAX 256

// ---------------------------------------------------------------------------
// Weight convert+transpose: W[K][N] f32 -> Wt[N][K] bf16.  64x64 LDS tile.
// ---------------------------------------------------------------------------
__global__ __launch_bounds__(256)
void wtrans_k(const float* __restrict__ W, bf16* __restrict__ Wt, int K, int N)
{
    __shared__ bf16 tile[64][72];
    const long mofs = (long)blockIdx.z * K * N;
    const float* Ws = W + mofs;
    bf16* Wo = Wt + mofs;
    const int n0 = blockIdx.x * 64, k0 = blockIdx.y * 64;
    const int t = threadIdx.x;
    {
        const int r = t >> 2, cc = (t & 3) * 16;
        const float* src = Ws + (long)(k0 + r) * N + n0 + cc;
#pragma unroll
        for (int i = 0; i < 2; ++i) {
            f32x4 a = *(const f32x4*)(src + i * 8);
            f32x4 b = *(const f32x4*)(src + i * 8 + 4);
            bf16x8 w;
            w[0]=(bf16)a.x; w[1]=(bf16)a.y; w[2]=(bf16)a.z; w[3]=(bf16)a.w;
            w[4]=(bf16)b.x; w[5]=(bf16)b.y; w[6]=(bf16)b.z; w[7]=(bf16)b.w;
            *(bf16x8*)&tile[r][cc + i * 8] = w;
        }
    }
    __syncthreads();
    {
        const int n = t >> 2, kc = (t & 3) * 16;
        bf16x8 o0, o1;
#pragma unroll
        for (int j = 0; j < 8; ++j) { o0[j] = tile[kc + j][n]; o1[j] = tile[kc + 8 + j][n]; }
        bf16* dst = Wo + (long)(n0 + n) * K + k0 + kc;
        *(bf16x8*)dst = o0;
        *(bf16x8*)(dst + 8) = o1;
    }
}

// ---------------------------------------------------------------------------
// bf16 MFMA GEMM, double-buffered LDS, optional split-K.
// C f32[*] = A[M,K] * Bt[N,K]^T for K-chunk blockIdx.z%KSPLIT.
// C offset = bsC * blockIdx.z (caller lays out partials).
// ---------------------------------------------------------------------------
template<int BM, int BN, int KSPLIT>
__global__ __launch_bounds__(256)
void gemm_k(const bf16* __restrict__ A, int lda, long bsA,
            const bf16* __restrict__ Bt, int ldb, long bsB,
            float* __restrict__ Cf, int ldc, long bsC,
            int K)
{
    constexpr int WC  = (BM == 128) ? 2 : 4;
    constexpr int WTN = BN / WC;
    constexpr int NF  = WTN / 16;
    __shared__ bf16 Al[2][BM * 32];
    __shared__ bf16 Bl[2][BN * 32];

    const int t    = threadIdx.x;
    const int lane = t & 63;
    const int wv   = t >> 6;
    const int wr   = wv / WC, wc = wv % WC;
    const int lrow = lane & 15, lk = lane >> 4;
    const int n0   = blockIdx.x * BN;
    const int m0   = blockIdx.y * BM;
    const int ks   = (KSPLIT > 1) ? (blockIdx.z % KSPLIT) : 0;
    const int bz   = (KSPLIT > 1) ? (blockIdx.z / KSPLIT) : blockIdx.z;
    const int Kc   = K / KSPLIT;

    const bf16* Ab = A  + bsA * bz + (long)ks * Kc;
    const bf16* Bb = Bt + bsB * bz + (long)ks * Kc;

    f32x4 acc[4][NF];
#pragma unroll
    for (int m = 0; m < 4; ++m)
#pragma unroll
        for (int n = 0; n < NF; ++n) acc[m][n] = f32x4{0.f, 0.f, 0.f, 0.f};

    const int sr = t >> 2, sc = (t & 3) * 8;

    auto stage = [&](int buf, int kk) {
#pragma unroll
        for (int i = 0; i < BM / 64; ++i)
            __builtin_amdgcn_global_load_lds(
                (const __attribute__((address_space(1))) void*)(Ab + (long)(m0 + sr + i * 64) * lda + kk + sc),
                (__attribute__((address_space(3))) void*)(&Al[buf][i * 2048 + t * 8]), 16, 0, 0);
#pragma unroll
        for (int i = 0; i < BN / 64; ++i)
            __builtin_amdgcn_global_load_lds(
                (const __attribute__((address_space(1))) void*)(Bb + (long)(n0 + sr + i * 64) * ldb + kk + sc),
                (__attribute__((address_space(3))) void*)(&Bl[buf][i * 2048 + t * 8]), 16, 0, 0);
    };

    stage(0, 0);
    __syncthreads();
    int cur = 0;
    for (int k0 = 0; k0 < Kc; k0 += 32) {
        if (k0 + 32 < Kc) stage(cur ^ 1, k0 + 32);   // prefetch; drained by the
                                                     // syncthreads AFTER compute
        bf16x8 af[4], bfv[NF];
#pragma unroll
        for (int m = 0; m < 4; ++m)
            af[m] = *(const bf16x8*)&Al[cur][(wr * 64 + m * 16 + lrow) * 32 + lk * 8];
#pragma unroll
        for (int n = 0; n < NF; ++n)
            bfv[n] = *(const bf16x8*)&Bl[cur][(wc * WTN + n * 16 + lrow) * 32 + lk * 8];
#pragma unroll
        for (int m = 0; m < 4; ++m)
#pragma unroll
            for (int n = 0; n < NF; ++n)
                acc[m][n] = __builtin_amdgcn_mfma_f32_16x16x32_bf16(af[m], bfv[n], acc[m][n], 0, 0, 0);
        __syncthreads();
        cur ^= 1;
    }

    float* Co = Cf + bsC * blockIdx.z;
#pragma unroll
    for (int m = 0; m < 4; ++m)
#pragma unroll
        for (int n = 0; n < NF; ++n) {
            const int c = n0 + wc * WTN + n * 16 + lrow;
#pragma unroll
            for (int q = 0; q < 4; ++q) {
                const int r = m0 + wr * 64 + m * 16 + lk * 4 + q;
                Co[(long)r * ldc + c] = acc[m][n][q];
            }
        }
}

// ---------------------------------------------------------------------------
// Fused: x[row] += sum_ks parts[ks][prow] (+bias); write x; LayerNorm -> xn.
// SCATTER: prow = rmap[row], skip rows with no entry. parts rows are 1024 wide.
// ---------------------------------------------------------------------------
template<int NS, bool BIAS, bool SCATTER>
__global__ __launch_bounds__(256)
void ln_add_k(float* __restrict__ x, const float* __restrict__ parts, long pstride,
              const float* __restrict__ bias, const int* __restrict__ rmap,
              const float* __restrict__ w, const float* __restrict__ b,
              bf16* __restrict__ o)
{
    int row  = blockIdx.x * 4 + (threadIdx.x >> 6);
    int lane = threadIdx.x & 63;
    f32x4* xr = (f32x4*)(x + (long)row * HID) + lane * 4;
    f32x4 v[4];
#pragma unroll
    for (int i = 0; i < 4; ++i) v[i] = xr[i];

    if (NS > 0) {
        int prow = SCATTER ? rmap[row] : row;
        if (!SCATTER || prow >= 0) {
            const float* pp = parts + (long)prow * 1024 + lane * 16;
#pragma unroll
            for (int ksi = 0; ksi < NS; ++ksi) {
                const f32x4* q = (const f32x4*)(pp + (long)ksi * pstride);
#pragma unroll
                for (int i = 0; i < 4; ++i) v[i] += q[i];
            }
            if (BIAS) {
                const f32x4* bb = (const f32x4*)bias + lane * 4;
#pragma unroll
                for (int i = 0; i < 4; ++i) v[i] += bb[i];
            }
#pragma unroll
            for (int i = 0; i < 4; ++i) xr[i] = v[i];
        }
    }

    float s = 0.f;
#pragma unroll
    for (int i = 0; i < 4; ++i) s += v[i].x + v[i].y + v[i].z + v[i].w;
    for (int m = 32; m; m >>= 1) s += __shfl_xor(s, m);
    float mean = s * (1.f / 1024.f);
    f32x4 d[4];
    float ss = 0.f;
#pragma unroll
    for (int i = 0; i < 4; ++i) {
        d[i] = v[i] - mean;
        ss += d[i].x * d[i].x + d[i].y * d[i].y + d[i].z * d[i].z + d[i].w * d[i].w;
    }
    for (int m = 32; m; m >>= 1) ss += __shfl_xor(ss, m);
    float rs = rsqrtf(ss * (1.f / 1024.f) + 1e-5f);
    const f32x4* wp = (const f32x4*)w + lane * 4;
    const f32x4* bp = (const f32x4*)b + lane * 4;
    bf16x8 o0, o1;
#pragma unroll
    for (int i = 0; i < 4; ++i) {
        f32x4 wv = wp[i], bv = bp[i];
        f32x4 e;
        e.x = d[i].x * rs * wv.x + bv.x; e.y = d[i].y * rs * wv.y + bv.y;
        e.z = d[i].z * rs * wv.z + bv.z; e.w = d[i].w * rs * wv.w + bv.w;
        if (i < 2) { o0[i*4+0]=(bf16)e.x; o0[i*4+1]=(bf16)e.y; o0[i*4+2]=(bf16)e.z; o0[i*4+3]=(bf16)e.w; }
        else       { int k=(i-2)*4; o1[k+0]=(bf16)e.x; o1[k+1]=(bf16)e.y; o1[k+2]=(bf16)e.z; o1[k+3]=(bf16)e.w; }
    }
    bf16* op = o + (long)row * HID + lane * 16;
    *(bf16x8*)op = o0;
    *(bf16x8*)(op + 8) = o1;
}

// sum of 2 f32 partials -> f32 (for qkv)
__global__ __launch_bounds__(256)
void red2_k(const float* __restrict__ p, float* __restrict__ out, int n4)
{
    int i = blockIdx.x * 256 + threadIdx.x;
    const f32x4* a = (const f32x4*)p;
    const f32x4* b = a + n4;
    ((f32x4*)out)[i] = a[i] + b[i];
}

// ffn1: hbuf = gelu(sum2 parts + b1)   [1024][4096]
__global__ __launch_bounds__(256)
void red_gelu_k(const float* __restrict__ p, const float* __restrict__ bias,
                bf16* __restrict__ out)
{
    int i = blockIdx.x * 256 + threadIdx.x;      // f32x4 index, 1,048,576 total
    f32x4 a = ((const f32x4*)p)[i];
    f32x4 c = ((const f32x4*)(p + 4194304))[i];
    f32x4 bb = ((const f32x4*)bias)[i & 1023];
    f32x4 u = a + c + bb;
    bf16x4 o;
    o[0] = (bf16)(0.5f * u.x * (1.f + erff(u.x * 0.70710678118654752f)));
    o[1] = (bf16)(0.5f * u.y * (1.f + erff(u.y * 0.70710678118654752f)));
    o[2] = (bf16)(0.5f * u.z * (1.f + erff(u.z * 0.70710678118654752f)));
    o[3] = (bf16)(0.5f * u.w * (1.f + erff(u.w * 0.70710678118654752f)));
    ((bf16x4*)out)[i] = o;
}

// PV: Oc[r][h][d] (bf16, [256][1024]) = sum_ks pvp[(h*4+ks)][r][d]
__global__ __launch_bounds__(256)
void red4pv_k(const float* __restrict__ p, bf16* __restrict__ Oc)
{
    int i = blockIdx.x * 256 + threadIdx.x;      // 65536 f32x4 groups
    int d4 = (i & 15) * 4;
    int r  = (i >> 4) & 255;
    int h  = i >> 12;
    const float* base = p + (long)(h * 4) * 16384 + r * 64 + d4;
    f32x4 s = *(const f32x4*)base;
    s += *(const f32x4*)(base + 16384);
    s += *(const f32x4*)(base + 32768);
    s += *(const f32x4*)(base + 49152);
    bf16x4 o;
    o[0] = (bf16)s.x; o[1] = (bf16)s.y; o[2] = (bf16)s.z; o[3] = (bf16)s.w;
    *(bf16x4*)(Oc + (long)r * 1024 + h * 64 + d4) = o;
}

// ---------------------------------------------------------------------------
// Local attention: one wave per (token, head).
// ---------------------------------------------------------------------------
__global__ __launch_bounds__(256)
void lattn_k(const float* __restrict__ qkv, bf16* __restrict__ ao)
{
    int w    = blockIdx.x * 4 + (threadIdx.x >> 6);
    int lane = threadIdx.x & 63;
    int n = w >> 4, h = w & 15;
    int tt = n >> 8, hh = (n >> 4) & 15, ww = n & 15;

    int nj = -1;
    float dotv = 0.f;
    if (lane < 27) {
        int dt = lane / 9 - 1, dh = (lane % 9) / 3 - 1, dw = lane % 3 - 1;
        int t2 = tt + dt, h2 = hh + dh, w2 = ww + dw;
        if (t2 >= 0 && t2 < 4 && h2 >= 0 && h2 < 16 && w2 >= 0 && w2 < 16)
            nj = (t2 << 8) | (h2 << 4) | w2;
    }
    if (nj >= 0) {
        const f32x4* qp = (const f32x4*)(qkv + (long)n * 3072 + h * 64);
        const f32x4* kp = (const f32x4*)(qkv + (long)nj * 3072 + 1024 + h * 64);
#pragma unroll
        for (int i = 0; i < 16; ++i) {
            f32x4 q4 = qp[i], k4 = kp[i];
            dotv += q4.x * k4.x + q4.y * k4.y + q4.z * k4.z + q4.w * k4.w;
        }
    }
    float sc = (lane < 27) ? dotv * 0.125f : -3.0e38f;
    float mx = sc;
    for (int m = 32; m; m >>= 1) mx = fmaxf(mx, __shfl_xor(mx, m));
    float e = (lane < 27) ? __expf(sc - mx) : 0.f;
    float s = e;
    for (int m = 32; m; m >>= 1) s += __shfl_xor(s, m);
    float p = e / s;

    float acc = 0.f;
    for (int j = 0; j < 27; ++j) {
        float pj = __shfl(p, j);
        int  njj = __shfl(nj, j);
        if (njj >= 0) acc += pj * qkv[(long)njj * 3072 + 2048 + h * 64 + lane];
    }
    ao[(long)n * 1024 + h * 64 + lane] = (bf16)acc;
}

// ---------------------------------------------------------------------------
__global__ void compact_k(const int* __restrict__ mask, int* __restrict__ qidx,
                          int* __restrict__ rmap)
{
    int lane = threadIdx.x;
    int total = 0;
    for (int base = 0; base < 1024; base += 64) {
        int m = (mask[base + lane] != 0) ? 1 : 0;
        unsigned long long bal = __ballot(m);
        int pos = total + (int)__popcll(bal & ((1ull << lane) - 1ull));
        int ok = (m && pos < QCMAX);
        if (ok) qidx[pos] = base + lane;
        rmap[base + lane] = ok ? pos : -1;
        total += (int)__popcll(bal);
    }
    for (int i = total + lane; i < QCMAX; i += 64) qidx[i] = -1;
}

// ---------------------------------------------------------------------------
__global__ __launch_bounds__(256)
void qbuild_k(const float* __restrict__ qkv, const int* __restrict__ qidx,
              bf16* __restrict__ Qc)
{
    const int h = blockIdx.y;
    const int t = threadIdx.x;
    const int r = blockIdx.x * 64 + (t >> 2), dc = (t & 3) * 16;
    const int q = qidx[r];
    bf16x8 o0, o1;
    if (q >= 0) {
        const f32x4* src = (const f32x4*)(qkv + (long)q * 3072 + h * 64 + dc);
#pragma unroll
        for (int i = 0; i < 2; ++i) {
            f32x4 a = src[i * 2] * 0.125f, b = src[i * 2 + 1] * 0.125f;
            bf16x8 w;
            w[0]=(bf16)a.x; w[1]=(bf16)a.y; w[2]=(bf16)a.z; w[3]=(bf16)a.w;
            w[4]=(bf16)b.x; w[5]=(bf16)b.y; w[6]=(bf16)b.z; w[7]=(bf16)b.w;
            if (i == 0) o0 = w; else o1 = w;
        }
    } else {
#pragma unroll
        for (int j = 0; j < 8; ++j) { o0[j] = (bf16)0.f; o1[j] = (bf16)0.f; }
    }
    bf16* dst = Qc + (long)h * (QCMAX * 64) + (long)r * 64 + dc;
    *(bf16x8*)dst = o0;
    *(bf16x8*)(dst + 8) = o1;
}

// ---------------------------------------------------------------------------
__global__ __launch_bounds__(256)
void kvbuild_k(const float* __restrict__ qkv, bf16* __restrict__ Kh,
               bf16* __restrict__ Vt)
{
    __shared__ bf16 vt[64][72];
    const int h = blockIdx.y;
    const int k0 = blockIdx.x * 64;
    const int t = threadIdx.x;
    {
        const int r = t >> 2, dc = (t & 3) * 16;
        const float* kp = qkv + (long)(k0 + r) * 3072 + 1024 + h * 64 + dc;
        const float* vp = kp + 1024;
        bf16x8 ko0, ko1;
#pragma unroll
        for (int i = 0; i < 2; ++i) {
            f32x4 a = *(const f32x4*)(kp + i * 8);
            f32x4 b = *(const f32x4*)(kp + i * 8 + 4);
            bf16x8 w;
            w[0]=(bf16)a.x; w[1]=(bf16)a.y; w[2]=(bf16)a.z; w[3]=(bf16)a.w;
            w[4]=(bf16)b.x; w[5]=(bf16)b.y; w[6]=(bf16)b.z; w[7]=(bf16)b.w;
            if (i == 0) ko0 = w; else ko1 = w;
        }
        bf16* kd = Kh + (long)h * (NTOK * 64) + (long)(k0 + r) * 64 + dc;
        *(bf16x8*)kd = ko0;
        *(bf16x8*)(kd + 8) = ko1;
#pragma unroll
        for (int i = 0; i < 2; ++i) {
            f32x4 a = *(const f32x4*)(vp + i * 8);
            f32x4 b = *(const f32x4*)(vp + i * 8 + 4);
            bf16x8 w;
            w[0]=(bf16)a.x; w[1]=(bf16)a.y; w[2]=(bf16)a.z; w[3]=(bf16)a.w;
            w[4]=(bf16)b.x; w[5]=(bf16)b.y; w[6]=(bf16)b.z; w[7]=(bf16)b.w;
            *(bf16x8*)&vt[r][dc + i * 8] = w;
        }
    }
    __syncthreads();
    {
        const int d = t >> 2, kc = (t & 3) * 16;
        bf16x8 o0, o1;
#pragma unroll
        for (int j = 0; j < 8; ++j) { o0[j] = vt[kc + j][d]; o1[j] = vt[kc + 8 + j][d]; }
        bf16* dst = Vt + (long)h * (64 * NTOK) + (long)d * NTOK + k0 + kc;
        *(bf16x8*)dst = o0;
        *(bf16x8*)(dst + 8) = o1;
    }
}

// ---------------------------------------------------------------------------
__global__ __launch_bounds__(256)
void softmax_k(const float* __restrict__ S, bf16* __restrict__ P)
{
    int row  = blockIdx.x * 4 + (threadIdx.x >> 6);
    int lane = threadIdx.x & 63;
    const f32x4* sp = (const f32x4*)(S + (long)row * 1024) + lane * 4;
    f32x4 v[4];
#pragma unroll
    for (int i = 0; i < 4; ++i) v[i] = sp[i];
    float mx = -3.0e38f;
#pragma unroll
    for (int i = 0; i < 4; ++i)
        mx = fmaxf(mx, fmaxf(fmaxf(v[i].x, v[i].y), fmaxf(v[i].z, v[i].w)));
    for (int m = 32; m; m >>= 1) mx = fmaxf(mx, __shfl_xor(mx, m));
    f32x4 ev[4];
    float sum = 0.f;
#pragma unroll
    for (int i = 0; i < 4; ++i) {
        ev[i].x = __expf(v[i].x - mx); ev[i].y = __expf(v[i].y - mx);
        ev[i].z = __expf(v[i].z - mx); ev[i].w = __expf(v[i].w - mx);
        sum += ev[i].x + ev[i].y + ev[i].z + ev[i].w;
    }
    for (int m = 32; m; m >>= 1) sum += __shfl_xor(sum, m);
    float inv = 1.f / sum;
    bf16x8 o0, o1;
#pragma unroll
    for (int i = 0; i < 4; ++i) {
        f32x4 e = ev[i] * inv;
        if (i < 2) { o0[i*4+0]=(bf16)e.x; o0[i*4+1]=(bf16)e.y; o0[i*4+2]=(bf16)e.z; o0[i*4+3]=(bf16)e.w; }
        else       { int k=(i-2)*4; o1[k+0]=(bf16)e.x; o1[k+1]=(bf16)e.y; o1[k+2]=(bf16)e.z; o1[k+3]=(bf16)e.w; }
    }
    bf16* op = P + (long)row * 1024 + lane * 16;
    *(bf16x8*)op = o0;
    *(bf16x8*)(op + 8) = o1;
}

// ---------------------------------------------------------------------------
__global__ __launch_bounds__(256)
void prep_k(const float* __restrict__ lat, const int* __restrict__ mask,
            const float* __restrict__ Wi, const float* __restrict__ bi,
            const float* __restrict__ et, const float* __restrict__ eh,
            const float* __restrict__ ew,
            float* __restrict__ x, float* __restrict__ tokens)
{
    __shared__ float tl[16][65];
    int t = threadIdx.x;
    int n0 = blockIdx.x * 16;
    for (int idx = t; idx < 16 * 65; idx += 256) {
        int ti = idx / 65, d = idx % 65;
        int n = n0 + ti;
        int tt = n >> 8, hh = (n >> 4) & 15, wwi = n & 15;
        float v;
        if (d < 64) {
            int c = d >> 2, ph = (d >> 1) & 1, pw = d & 1;
            v = lat[(((long)tt * 16 + c) * 32 + hh * 2 + ph) * 32 + wwi * 2 + pw];
            tokens[(long)n * 64 + d] = v;
        } else {
            v = mask[n] ? 1.f : 0.f;
        }
        tl[ti][d] = v;
    }
    __syncthreads();
    f32x4 acc[16];
#pragma unroll
    for (int i = 0; i < 16; ++i) acc[i] = f32x4{0.f, 0.f, 0.f, 0.f};
    for (int d = 0; d < 65; ++d) {
        f32x4 wv = *(const f32x4*)(Wi + (long)d * 1024 + t * 4);
#pragma unroll
        for (int ti = 0; ti < 16; ++ti) acc[ti] += tl[ti][d] * wv;
    }
    f32x4 bb = *(const f32x4*)(bi + t * 4);
    for (int ti = 0; ti < 16; ++ti) {
        int n = n0 + ti;
        int tt = n >> 8, hh = (n >> 4) & 15, wwi = n & 15;
        f32x4 pos = *(const f32x4*)(et + (long)tt * 1024 + t * 4)
                  + *(const f32x4*)(eh + (long)hh * 1024 + t * 4)
                  + *(const f32x4*)(ew + (long)wwi * 1024 + t * 4);
        *(f32x4*)(x + (long)n * 1024 + t * 4) = acc[ti] + bb + pos;
    }
}

// ---------------------------------------------------------------------------
__global__ __launch_bounds__(256)
void final_k(const bf16* __restrict__ xn, const float* __restrict__ OW,
             const float* __restrict__ ob, const float* __restrict__ tokens,
             float* __restrict__ out)
{
    __shared__ bf16 xl[8][1024];
    __shared__ float part[4][8][64];
    int t = threadIdx.x;
    int n0 = blockIdx.x * 8;
    for (int i = t; i < 1024; i += 256)
        ((u32x4*)xl)[i] = ((const u32x4*)(xn + (long)n0 * 1024))[i];
    __syncthreads();
    int j = t & 63, s = t >> 6;
    float acc[8] = {0.f, 0.f, 0.f, 0.f, 0.f, 0.f, 0.f, 0.f};
    for (int k = s * 256; k < s * 256 + 256; ++k) {
        float w = OW[(long)k * 64 + j];
#pragma unroll
        for (int ti = 0; ti < 8; ++ti) acc[ti] += (float)xl[ti][k] * w;
    }
    for (int ti = 0; ti < 8; ++ti) part[s][ti][j] = acc[ti];
    __syncthreads();
    if (s == 0) {
        for (int ti = 0; ti < 8; ++ti) {
            int n = n0 + ti;
            float v = part[0][ti][j] + part[1][ti][j] + part[2][ti][j] + part[3][ti][j]
                    + ob[j] + tokens[(long)n * 64 + j];
            int tt = n >> 8, hh = (n >> 4) & 15, wwi = n & 15;
            int c = j >> 2, ph = (j >> 1) & 1, pw = j & 1;
            out[(((long)tt * 16 + c) * 32 + hh * 2 + ph) * 32 + wwi * 2 + pw] = v;
        }
    }
}

// ---------------------------------------------------------------------------
extern "C" void kernel_launch(void* const* d_in, const int* in_sizes, int n_in,
                              void* d_out, int out_size, void* d_ws, size_t ws_size,
                              hipStream_t stream)
{
    const float* latents = (const float*)d_in[0];
    const int*   mask    = (const int*)d_in[1];
    const float* ipw  = (const float*)d_in[2];
    const float* ipb  = (const float*)d_in[3];
    const float* et   = (const float*)d_in[4];
    const float* eh   = (const float*)d_in[5];
    const float* ew   = (const float*)d_in[6];
    const float* lnlw = (const float*)d_in[7];
    const float* lnlb = (const float*)d_in[8];
    const float* lngw = (const float*)d_in[9];
    const float* lngb = (const float*)d_in[10];
    const float* lnfw = (const float*)d_in[11];
    const float* lnfb = (const float*)d_in[12];
    const float* lqkv = (const float*)d_in[13];
    const float* lout = (const float*)d_in[14];
    const float* gqkv = (const float*)d_in[15];
    const float* gout = (const float*)d_in[16];
    const float* w1   = (const float*)d_in[17];
    const float* b1   = (const float*)d_in[18];
    const float* w2   = (const float*)d_in[19];
    const float* b2   = (const float*)d_in[20];
    const float* flw  = (const float*)d_in[21];
    const float* flb  = (const float*)d_in[22];
    const float* opw  = (const float*)d_in[23];
    const float* opb  = (const float*)d_in[24];

    char* p = (char*)d_ws;
    auto alloc = [&](size_t bytes) { char* r = p; p += (bytes + 255) & ~(size_t)255; return r; };
    float* x      = (float*)alloc((size_t)4 << 20);
    bf16*  xn     = (bf16*)alloc((size_t)2 << 20);
    float* qkv    = (float*)alloc((size_t)12 << 20);
    bf16*  ao     = (bf16*)alloc((size_t)2 << 20);
    bf16*  hbuf   = (bf16*)alloc((size_t)8 << 20);
    float* tokens = (float*)alloc((size_t)256 << 10);
    bf16*  Qc     = (bf16*)alloc((size_t)512 << 10);
    bf16*  Kh     = (bf16*)alloc((size_t)2 << 20);
    bf16*  Vt     = (bf16*)alloc((size_t)2 << 20);
    float* S      = (float*)alloc((size_t)16 << 20);
    bf16*  P      = (bf16*)alloc((size_t)8 << 20);
    bf16*  Oc     = (bf16*)alloc((size_t)512 << 10);
    int*   qidx   = (int*)alloc(4096);
    int*   rmap   = (int*)alloc(4096);
    // split-K partial buffers (f32)
    float* qkvp  = (float*)alloc((size_t)2 * 1024 * 3072 * 4);
    float* loutp = (float*)alloc((size_t)2 * 1024 * 1024 * 4);
    float* goutp = (float*)alloc((size_t)4 * 256 * 1024 * 4);
    float* pvp   = (float*)alloc((size_t)64 * 256 * 64 * 4);
    float* f1p   = (float*)alloc((size_t)2 * 1024 * 4096 * 4);
    float* f2p   = (float*)alloc((size_t)4 * 1024 * 1024 * 4);
    // bf16 transposed weights Wt[N][K]
    bf16* lqkvT = (bf16*)alloc((size_t)10 * 3072 * 1024 * 2);
    bf16* loutT = (bf16*)alloc((size_t)10 * 1024 * 1024 * 2);
    bf16* gqkvT = (bf16*)alloc((size_t)10 * 3072 * 1024 * 2);
    bf16* goutT = (bf16*)alloc((size_t)10 * 1024 * 1024 * 2);
    bf16* w1T   = (bf16*)alloc((size_t)10 * 4096 * 1024 * 2);
    bf16* w2T   = (bf16*)alloc((size_t)10 * 1024 * 4096 * 2);

    wtrans_k<<<dim3(48, 16, NL), 256, 0, stream>>>(lqkv, lqkvT, 1024, 3072);
    wtrans_k<<<dim3(16, 16, NL), 256, 0, stream>>>(lout, loutT, 1024, 1024);
    wtrans_k<<<dim3(48, 16, NL), 256, 0, stream>>>(gqkv, gqkvT, 1024, 3072);
    wtrans_k<<<dim3(16, 16, NL), 256, 0, stream>>>(gout, goutT, 1024, 1024);
    wtrans_k<<<dim3(64, 16, NL), 256, 0, stream>>>(w1, w1T, 1024, 4096);
    wtrans_k<<<dim3(16, 64, NL), 256, 0, stream>>>(w2, w2T, 4096, 1024);

    prep_k<<<64, 256, 0, stream>>>(latents, mask, ipw, ipb, et, eh, ew, x, tokens);
    compact_k<<<1, 64, 0, stream>>>(mask, qidx, rmap);

    for (int l = 0; l < NL; ++l) {
        const long wq  = (long)l * 3072 * 1024;
        const long wo  = (long)l * 1024 * 1024;
        const long wf1 = (long)l * 4096 * 1024;

        // lnA: fold previous layer's ffn2 partials (+b2) into x, then LN
        if (l == 0)
            ln_add_k<0, false, false><<<256, 256, 0, stream>>>(
                x, nullptr, 0, nullptr, nullptr, lnlw, lnlb, xn);
        else
            ln_add_k<4, true, false><<<256, 256, 0, stream>>>(
                x, f2p, (long)1024 * 1024, b2 + (l - 1) * 1024, nullptr,
                lnlw + l * HID, lnlb + l * HID, xn);

        // local attention
        gemm_k<128, 128, 2><<<dim3(24, 8, 2), 256, 0, stream>>>(
            xn, 1024, 0, lqkvT + wq, 1024, 0, qkvp, 3072, (long)1024 * 3072, 1024);
        red2_k<<<3072, 256, 0, stream>>>(qkvp, qkv, 1024 * 3072 / 4);
        lattn_k<<<4096, 256, 0, stream>>>(qkv, ao);
        gemm_k<64, 128, 2><<<dim3(8, 16, 2), 256, 0, stream>>>(
            ao, 1024, 0, loutT + wo, 1024, 0, loutp, 1024, (long)1024 * 1024, 1024);

        // lnB: fold local-out partials
        ln_add_k<2, false, false><<<256, 256, 0, stream>>>(
            x, loutp, (long)1024 * 1024, nullptr, nullptr,
            lngw + l * HID, lngb + l * HID, xn);

        // global attention (masked queries)
        gemm_k<128, 128, 2><<<dim3(24, 8, 2), 256, 0, stream>>>(
            xn, 1024, 0, gqkvT + wq, 1024, 0, qkvp, 3072, (long)1024 * 3072, 1024);
        red2_k<<<3072, 256, 0, stream>>>(qkvp, qkv, 1024 * 3072 / 4);
        qbuild_k<<<dim3(4, 16), 256, 0, stream>>>(qkv, qidx, Qc);
        kvbuild_k<<<dim3(16, 16), 256, 0, stream>>>(qkv, Kh, Vt);
        gemm_k<64, 128, 1><<<dim3(8, 4, 16), 256, 0, stream>>>(
            Qc, 64, (long)256 * 64, Kh, 64, (long)1024 * 64,
            S, 1024, (long)256 * 1024, 64);
        softmax_k<<<1024, 256, 0, stream>>>(S, P);
        gemm_k<64, 64, 4><<<dim3(1, 4, 64), 256, 0, stream>>>(
            P, 1024, (long)256 * 1024, Vt, 1024, (long)64 * 1024,
            pvp, 64, (long)256 * 64, 1024);
        red4pv_k<<<256, 256, 0, stream>>>(pvp, Oc);
        gemm_k<64, 64, 4><<<dim3(16, 4, 4), 256, 0, stream>>>(
            Oc, 1024, 0, goutT + wo, 1024, 0, goutp, 1024, (long)256 * 1024, 1024);

        // lnC: scatter-fold global-out partials via rmap
        ln_add_k<4, false, true><<<256, 256, 0, stream>>>(
            x, goutp, (long)256 * 1024, nullptr, rmap,
            lnfw + l * HID, lnfb + l * HID, xn);

        // FFN
        gemm_k<128, 128, 2><<<dim3(32, 8, 2), 256, 0, stream>>>(
            xn, 1024, 0, w1T + wf1, 1024, 0, f1p, 4096, (long)1024 * 4096, 1024);
        red_gelu_k<<<4096, 256, 0, stream>>>(f1p, b1 + l * 4096, hbuf);
        gemm_k<64, 128, 4><<<dim3(8, 16, 4), 256, 0, stream>>>(
            hbuf, 4096, 0, w2T + wf1, 4096, 0, f2p, 1024, (long)1024 * 1024, 4096);
    }

    // final LN folds last ffn2 partials (+b2[9])
    ln_add_k<4, true, false><<<256, 256, 0, stream>>>(
        x, f2p, (long)1024 * 1024, b2 + 9 * 1024, nullptr, flw, flb, xn);
    final_k<<<128, 256, 0, stream>>>(xn, opw, opb, tokens, (float*)d_out);
}

// Round 4
// 2225.261 us; speedup vs baseline: 2.4628x; 1.0337x over previous
//
#include <hip/hip_runtime.h>
#include <hip/hip_bf16.h>
#include <math.h>

typedef __bf16 bf16;
typedef __bf16 bf16x8 __attribute__((ext_vector_type(8)));
typedef __bf16 bf16x4 __attribute__((ext_vector_type(4)));
typedef float  f32x4 __attribute__((ext_vector_type(4)));
typedef unsigned int u32x4 __attribute__((ext_vector_type(4)));

#define NTOK 1024
#define HID  1024
#define NH   16
#define HD   64
#define NL   10
#define QCMAX 256

#define EPI_F32  0
#define EPI_GELU 1

// ---------------------------------------------------------------------------
// Weight convert+transpose: W[K][N] f32 -> Wt[N][K] bf16.  64x64 LDS tile.
// ---------------------------------------------------------------------------
__global__ __launch_bounds__(256)
void wtrans_k(const float* __restrict__ W, bf16* __restrict__ Wt, int K, int N)
{
    __shared__ bf16 tile[64][72];
    const long mofs = (long)blockIdx.z * K * N;
    const float* Ws = W + mofs;
    bf16* Wo = Wt + mofs;
    const int n0 = blockIdx.x * 64, k0 = blockIdx.y * 64;
    const int t = threadIdx.x;
    {
        const int r = t >> 2, cc = (t & 3) * 16;
        const float* src = Ws + (long)(k0 + r) * N + n0 + cc;
#pragma unroll
        for (int i = 0; i < 2; ++i) {
            f32x4 a = *(const f32x4*)(src + i * 8);
            f32x4 b = *(const f32x4*)(src + i * 8 + 4);
            bf16x8 w;
            w[0]=(bf16)a.x; w[1]=(bf16)a.y; w[2]=(bf16)a.z; w[3]=(bf16)a.w;
            w[4]=(bf16)b.x; w[5]=(bf16)b.y; w[6]=(bf16)b.z; w[7]=(bf16)b.w;
            *(bf16x8*)&tile[r][cc + i * 8] = w;
        }
    }
    __syncthreads();
    {
        const int n = t >> 2, kc = (t & 3) * 16;
        bf16x8 o0, o1;
#pragma unroll
        for (int j = 0; j < 8; ++j) { o0[j] = tile[kc + j][n]; o1[j] = tile[kc + 8 + j][n]; }
        bf16* dst = Wo + (long)(n0 + n) * K + k0 + kc;
        *(bf16x8*)dst = o0;
        *(bf16x8*)(dst + 8) = o1;
    }
}

// ---------------------------------------------------------------------------
// bf16 MFMA GEMM, double-buffered LDS, optional split-K, fused epilogue.
// C = A[M,K] * Bt[N,K]^T for K-chunk (blockIdx.z % KSPLIT).
// C offset = bsC * blockIdx.z (caller lays out batch/partials).
// ---------------------------------------------------------------------------
template<int EPI, int BM, int BN, int KSPLIT>
__global__ __launch_bounds__(256)
void gemm_k(const bf16* __restrict__ A, int lda, long bsA,
            const bf16* __restrict__ Bt, int ldb, long bsB,
            void* __restrict__ Cv, int ldc, long bsC,
            const float* __restrict__ bias, int K)
{
    constexpr int WC  = (BM == 128) ? 2 : 4;
    constexpr int WTN = BN / WC;
    constexpr int NF  = WTN / 16;
    __shared__ bf16 Al[2][BM * 32];
    __shared__ bf16 Bl[2][BN * 32];

    const int t    = threadIdx.x;
    const int lane = t & 63;
    const int wv   = t >> 6;
    const int wr   = wv / WC, wc = wv % WC;
    const int lrow = lane & 15, lk = lane >> 4;
    const int n0   = blockIdx.x * BN;
    const int m0   = blockIdx.y * BM;
    const int ks   = (KSPLIT > 1) ? (blockIdx.z % KSPLIT) : 0;
    const int bz   = (KSPLIT > 1) ? (blockIdx.z / KSPLIT) : blockIdx.z;
    const int Kc   = K / KSPLIT;

    const bf16* Ab = A  + bsA * bz + (long)ks * Kc;
    const bf16* Bb = Bt + bsB * bz + (long)ks * Kc;

    f32x4 acc[4][NF];
#pragma unroll
    for (int m = 0; m < 4; ++m)
#pragma unroll
        for (int n = 0; n < NF; ++n) acc[m][n] = f32x4{0.f, 0.f, 0.f, 0.f};

    const int sr = t >> 2, sc = (t & 3) * 8;

    auto stage = [&](int buf, int kk) {
#pragma unroll
        for (int i = 0; i < BM / 64; ++i)
            __builtin_amdgcn_global_load_lds(
                (const __attribute__((address_space(1))) void*)(Ab + (long)(m0 + sr + i * 64) * lda + kk + sc),
                (__attribute__((address_space(3))) void*)(&Al[buf][i * 2048 + t * 8]), 16, 0, 0);
#pragma unroll
        for (int i = 0; i < BN / 64; ++i)
            __builtin_amdgcn_global_load_lds(
                (const __attribute__((address_space(1))) void*)(Bb + (long)(n0 + sr + i * 64) * ldb + kk + sc),
                (__attribute__((address_space(3))) void*)(&Bl[buf][i * 2048 + t * 8]), 16, 0, 0);
    };

    stage(0, 0);
    __syncthreads();
    int cur = 0;
    for (int k0 = 0; k0 < Kc; k0 += 32) {
        if (k0 + 32 < Kc) stage(cur ^ 1, k0 + 32);
        bf16x8 af[4], bfv[NF];
#pragma unroll
        for (int m = 0; m < 4; ++m)
            af[m] = *(const bf16x8*)&Al[cur][(wr * 64 + m * 16 + lrow) * 32 + lk * 8];
#pragma unroll
        for (int n = 0; n < NF; ++n)
            bfv[n] = *(const bf16x8*)&Bl[cur][(wc * WTN + n * 16 + lrow) * 32 + lk * 8];
#pragma unroll
        for (int m = 0; m < 4; ++m)
#pragma unroll
            for (int n = 0; n < NF; ++n)
                acc[m][n] = __builtin_amdgcn_mfma_f32_16x16x32_bf16(af[m], bfv[n], acc[m][n], 0, 0, 0);
        __syncthreads();
        cur ^= 1;
    }

    float* Cf = (float*)Cv + bsC * blockIdx.z;
    bf16*  Cb = (bf16*)Cv + bsC * blockIdx.z;
#pragma unroll
    for (int m = 0; m < 4; ++m)
#pragma unroll
        for (int n = 0; n < NF; ++n) {
            const int c = n0 + wc * WTN + n * 16 + lrow;
#pragma unroll
            for (int q = 0; q < 4; ++q) {
                const int r = m0 + wr * 64 + m * 16 + lk * 4 + q;
                const float v = acc[m][n][q];
                const long off = (long)r * ldc + c;
                if (EPI == EPI_F32) Cf[off] = v;
                else {
                    float u = v + bias[c];
                    Cb[off] = (bf16)(0.5f * u * (1.f + erff(u * 0.70710678118654752f)));
                }
            }
        }
}

// ---------------------------------------------------------------------------
// Fused: x[row] += sum_ks parts[ks][prow] (+bias); write x; LayerNorm -> xn.
// SCATTER: prow = rmap[row], skip rows with no entry.
// ---------------------------------------------------------------------------
template<int NS, bool BIAS, bool SCATTER>
__global__ __launch_bounds__(256)
void ln_add_k(float* __restrict__ x, const float* __restrict__ parts, long pstride,
              const float* __restrict__ bias, const int* __restrict__ rmap,
              const float* __restrict__ w, const float* __restrict__ b,
              bf16* __restrict__ o)
{
    int row  = blockIdx.x * 4 + (threadIdx.x >> 6);
    int lane = threadIdx.x & 63;
    f32x4* xr = (f32x4*)(x + (long)row * HID) + lane * 4;
    f32x4 v[4];
#pragma unroll
    for (int i = 0; i < 4; ++i) v[i] = xr[i];

    if (NS > 0) {
        int prow = SCATTER ? rmap[row] : row;
        if (!SCATTER || prow >= 0) {
            const float* pp = parts + (long)prow * 1024 + lane * 16;
#pragma unroll
            for (int ksi = 0; ksi < NS; ++ksi) {
                const f32x4* q = (const f32x4*)(pp + (long)ksi * pstride);
#pragma unroll
                for (int i = 0; i < 4; ++i) v[i] += q[i];
            }
            if (BIAS) {
                const f32x4* bb = (const f32x4*)bias + lane * 4;
#pragma unroll
                for (int i = 0; i < 4; ++i) v[i] += bb[i];
            }
#pragma unroll
            for (int i = 0; i < 4; ++i) xr[i] = v[i];
        }
    }

    float s = 0.f;
#pragma unroll
    for (int i = 0; i < 4; ++i) s += v[i].x + v[i].y + v[i].z + v[i].w;
    for (int m = 32; m; m >>= 1) s += __shfl_xor(s, m);
    float mean = s * (1.f / 1024.f);
    f32x4 d[4];
    float ss = 0.f;
#pragma unroll
    for (int i = 0; i < 4; ++i) {
        d[i] = v[i] - mean;
        ss += d[i].x * d[i].x + d[i].y * d[i].y + d[i].z * d[i].z + d[i].w * d[i].w;
    }
    for (int m = 32; m; m >>= 1) ss += __shfl_xor(ss, m);
    float rs = rsqrtf(ss * (1.f / 1024.f) + 1e-5f);
    const f32x4* wp = (const f32x4*)w + lane * 4;
    const f32x4* bp = (const f32x4*)b + lane * 4;
    bf16x8 o0, o1;
#pragma unroll
    for (int i = 0; i < 4; ++i) {
        f32x4 wv = wp[i], bv = bp[i];
        f32x4 e;
        e.x = d[i].x * rs * wv.x + bv.x; e.y = d[i].y * rs * wv.y + bv.y;
        e.z = d[i].z * rs * wv.z + bv.z; e.w = d[i].w * rs * wv.w + bv.w;
        if (i < 2) { o0[i*4+0]=(bf16)e.x; o0[i*4+1]=(bf16)e.y; o0[i*4+2]=(bf16)e.z; o0[i*4+3]=(bf16)e.w; }
        else       { int k=(i-2)*4; o1[k+0]=(bf16)e.x; o1[k+1]=(bf16)e.y; o1[k+2]=(bf16)e.z; o1[k+3]=(bf16)e.w; }
    }
    bf16* op = o + (long)row * HID + lane * 16;
    *(bf16x8*)op = o0;
    *(bf16x8*)(op + 8) = o1;
}

// PV: Oc[r][h][d] (bf16, [256][1024]) = sum_ks pvp[(h*4+ks)][r][d]
__global__ __launch_bounds__(256)
void red4pv_k(const float* __restrict__ p, bf16* __restrict__ Oc)
{
    int i = blockIdx.x * 256 + threadIdx.x;
    int d4 = (i & 15) * 4;
    int r  = (i >> 4) & 255;
    int h  = i >> 12;
    const float* base = p + (long)(h * 4) * 16384 + r * 64 + d4;
    f32x4 s = *(const f32x4*)base;
    s += *(const f32x4*)(base + 16384);
    s += *(const f32x4*)(base + 32768);
    s += *(const f32x4*)(base + 49152);
    bf16x4 o;
    o[0] = (bf16)s.x; o[1] = (bf16)s.y; o[2] = (bf16)s.z; o[3] = (bf16)s.w;
    *(bf16x4*)(Oc + (long)r * 1024 + h * 64 + d4) = o;
}

// ---------------------------------------------------------------------------
// Local attention: one wave per (token, head).
// ---------------------------------------------------------------------------
__global__ __launch_bounds__(256)
void lattn_k(const float* __restrict__ qkv, bf16* __restrict__ ao)
{
    int w    = blockIdx.x * 4 + (threadIdx.x >> 6);
    int lane = threadIdx.x & 63;
    int n = w >> 4, h = w & 15;
    int tt = n >> 8, hh = (n >> 4) & 15, ww = n & 15;

    int nj = -1;
    float dotv = 0.f;
    if (lane < 27) {
        int dt = lane / 9 - 1, dh = (lane % 9) / 3 - 1, dw = lane % 3 - 1;
        int t2 = tt + dt, h2 = hh + dh, w2 = ww + dw;
        if (t2 >= 0 && t2 < 4 && h2 >= 0 && h2 < 16 && w2 >= 0 && w2 < 16)
            nj = (t2 << 8) | (h2 << 4) | w2;
    }
    if (nj >= 0) {
        const f32x4* qp = (const f32x4*)(qkv + (long)n * 3072 + h * 64);
        const f32x4* kp = (const f32x4*)(qkv + (long)nj * 3072 + 1024 + h * 64);
#pragma unroll
        for (int i = 0; i < 16; ++i) {
            f32x4 q4 = qp[i], k4 = kp[i];
            dotv += q4.x * k4.x + q4.y * k4.y + q4.z * k4.z + q4.w * k4.w;
        }
    }
    float sc = (lane < 27) ? dotv * 0.125f : -3.0e38f;
    float mx = sc;
    for (int m = 32; m; m >>= 1) mx = fmaxf(mx, __shfl_xor(mx, m));
    float e = (lane < 27) ? __expf(sc - mx) : 0.f;
    float s = e;
    for (int m = 32; m; m >>= 1) s += __shfl_xor(s, m);
    float p = e / s;

    float acc = 0.f;
    for (int j = 0; j < 27; ++j) {
        float pj = __shfl(p, j);
        int  njj = __shfl(nj, j);
        if (njj >= 0) acc += pj * qkv[(long)njj * 3072 + 2048 + h * 64 + lane];
    }
    ao[(long)n * 1024 + h * 64 + lane] = (bf16)acc;
}

// ---------------------------------------------------------------------------
__global__ void compact_k(const int* __restrict__ mask, int* __restrict__ qidx,
                          int* __restrict__ rmap)
{
    int lane = threadIdx.x;
    int total = 0;
    for (int base = 0; base < 1024; base += 64) {
        int m = (mask[base + lane] != 0) ? 1 : 0;
        unsigned long long bal = __ballot(m);
        int pos = total + (int)__popcll(bal & ((1ull << lane) - 1ull));
        int ok = (m && pos < QCMAX);
        if (ok) qidx[pos] = base + lane;
        rmap[base + lane] = ok ? pos : -1;
        total += (int)__popcll(bal);
    }
    for (int i = total + lane; i < QCMAX; i += 64) qidx[i] = -1;
}

// ---------------------------------------------------------------------------
// Merged Q/K/V head-layout build.
// blockIdx.x < 4: Qc[h][r][d] = 0.125*qkv[qidx[r]][q,h,d]  (4 row-tiles)
// else: Kh[h][tok][d], Vt[h][d][tok]                        (16 tok-tiles)
// ---------------------------------------------------------------------------
__global__ __launch_bounds__(256)
void qkvbuild_k(const float* __restrict__ qkv, const int* __restrict__ qidx,
                bf16* __restrict__ Qc, bf16* __restrict__ Kh, bf16* __restrict__ Vt)
{
    __shared__ bf16 vt[64][72];
    const int h = blockIdx.y;
    const int t = threadIdx.x;
    if (blockIdx.x < 4) {
        const int r = blockIdx.x * 64 + (t >> 2), dc = (t & 3) * 16;
        const int q = qidx[r];
        bf16x8 o0, o1;
        if (q >= 0) {
            const f32x4* src = (const f32x4*)(qkv + (long)q * 3072 + h * 64 + dc);
#pragma unroll
            for (int i = 0; i < 2; ++i) {
                f32x4 a = src[i * 2] * 0.125f, b = src[i * 2 + 1] * 0.125f;
                bf16x8 w;
                w[0]=(bf16)a.x; w[1]=(bf16)a.y; w[2]=(bf16)a.z; w[3]=(bf16)a.w;
                w[4]=(bf16)b.x; w[5]=(bf16)b.y; w[6]=(bf16)b.z; w[7]=(bf16)b.w;
                if (i == 0) o0 = w; else o1 = w;
            }
        } else {
#pragma unroll
            for (int j = 0; j < 8; ++j) { o0[j] = (bf16)0.f; o1[j] = (bf16)0.f; }
        }
        bf16* dst = Qc + (long)h * (QCMAX * 64) + (long)r * 64 + dc;
        *(bf16x8*)dst = o0;
        *(bf16x8*)(dst + 8) = o1;
        return;
    }
    const int k0 = (blockIdx.x - 4) * 64;
    {
        const int r = t >> 2, dc = (t & 3) * 16;
        const float* kp = qkv + (long)(k0 + r) * 3072 + 1024 + h * 64 + dc;
        const float* vp = kp + 1024;
        bf16x8 ko0, ko1;
#pragma unroll
        for (int i = 0; i < 2; ++i) {
            f32x4 a = *(const f32x4*)(kp + i * 8);
            f32x4 b = *(const f32x4*)(kp + i * 8 + 4);
            bf16x8 w;
            w[0]=(bf16)a.x; w[1]=(bf16)a.y; w[2]=(bf16)a.z; w[3]=(bf16)a.w;
            w[4]=(bf16)b.x; w[5]=(bf16)b.y; w[6]=(bf16)b.z; w[7]=(bf16)b.w;
            if (i == 0) ko0 = w; else ko1 = w;
        }
        bf16* kd = Kh + (long)h * (NTOK * 64) + (long)(k0 + r) * 64 + dc;
        *(bf16x8*)kd = ko0;
        *(bf16x8*)(kd + 8) = ko1;
#pragma unroll
        for (int i = 0; i < 2; ++i) {
            f32x4 a = *(const f32x4*)(vp + i * 8);
            f32x4 b = *(const f32x4*)(vp + i * 8 + 4);
            bf16x8 w;
            w[0]=(bf16)a.x; w[1]=(bf16)a.y; w[2]=(bf16)a.z; w[3]=(bf16)a.w;
            w[4]=(bf16)b.x; w[5]=(bf16)b.y; w[6]=(bf16)b.z; w[7]=(bf16)b.w;
            *(bf16x8*)&vt[r][dc + i * 8] = w;
        }
    }
    __syncthreads();
    {
        const int d = t >> 2, kc = (t & 3) * 16;
        bf16x8 o0, o1;
#pragma unroll
        for (int j = 0; j < 8; ++j) { o0[j] = vt[kc + j][d]; o1[j] = vt[kc + 8 + j][d]; }
        bf16* dst = Vt + (long)h * (64 * NTOK) + (long)d * NTOK + k0 + kc;
        *(bf16x8*)dst = o0;
        *(bf16x8*)(dst + 8) = o1;
    }
}

// ---------------------------------------------------------------------------
__global__ __launch_bounds__(256)
void softmax_k(const float* __restrict__ S, bf16* __restrict__ P)
{
    int row  = blockIdx.x * 4 + (threadIdx.x >> 6);
    int lane = threadIdx.x & 63;
    const f32x4* sp = (const f32x4*)(S + (long)row * 1024) + lane * 4;
    f32x4 v[4];
#pragma unroll
    for (int i = 0; i < 4; ++i) v[i] = sp[i];
    float mx = -3.0e38f;
#pragma unroll
    for (int i = 0; i < 4; ++i)
        mx = fmaxf(mx, fmaxf(fmaxf(v[i].x, v[i].y), fmaxf(v[i].z, v[i].w)));
    for (int m = 32; m; m >>= 1) mx = fmaxf(mx, __shfl_xor(mx, m));
    f32x4 ev[4];
    float sum = 0.f;
#pragma unroll
    for (int i = 0; i < 4; ++i) {
        ev[i].x = __expf(v[i].x - mx); ev[i].y = __expf(v[i].y - mx);
        ev[i].z = __expf(v[i].z - mx); ev[i].w = __expf(v[i].w - mx);
        sum += ev[i].x + ev[i].y + ev[i].z + ev[i].w;
    }
    for (int m = 32; m; m >>= 1) sum += __shfl_xor(sum, m);
    float inv = 1.f / sum;
    bf16x8 o0, o1;
#pragma unroll
    for (int i = 0; i < 4; ++i) {
        f32x4 e = ev[i] * inv;
        if (i < 2) { o0[i*4+0]=(bf16)e.x; o0[i*4+1]=(bf16)e.y; o0[i*4+2]=(bf16)e.z; o0[i*4+3]=(bf16)e.w; }
        else       { int k=(i-2)*4; o1[k+0]=(bf16)e.x; o1[k+1]=(bf16)e.y; o1[k+2]=(bf16)e.z; o1[k+3]=(bf16)e.w; }
    }
    bf16* op = P + (long)row * 1024 + lane * 16;
    *(bf16x8*)op = o0;
    *(bf16x8*)(op + 8) = o1;
}

// ---------------------------------------------------------------------------
__global__ __launch_bounds__(256)
void prep_k(const float* __restrict__ lat, const int* __restrict__ mask,
            const float* __restrict__ Wi, const float* __restrict__ bi,
            const float* __restrict__ et, const float* __restrict__ eh,
            const float* __restrict__ ew,
            float* __restrict__ x, float* __restrict__ tokens)
{
    __shared__ float tl[16][65];
    int t = threadIdx.x;
    int n0 = blockIdx.x * 16;
    for (int idx = t; idx < 16 * 65; idx += 256) {
        int ti = idx / 65, d = idx % 65;
        int n = n0 + ti;
        int tt = n >> 8, hh = (n >> 4) & 15, wwi = n & 15;
        float v;
        if (d < 64) {
            int c = d >> 2, ph = (d >> 1) & 1, pw = d & 1;
            v = lat[(((long)tt * 16 + c) * 32 + hh * 2 + ph) * 32 + wwi * 2 + pw];
            tokens[(long)n * 64 + d] = v;
        } else {
            v = mask[n] ? 1.f : 0.f;
        }
        tl[ti][d] = v;
    }
    __syncthreads();
    f32x4 acc[16];
#pragma unroll
    for (int i = 0; i < 16; ++i) acc[i] = f32x4{0.f, 0.f, 0.f, 0.f};
    for (int d = 0; d < 65; ++d) {
        f32x4 wv = *(const f32x4*)(Wi + (long)d * 1024 + t * 4);
#pragma unroll
        for (int ti = 0; ti < 16; ++ti) acc[ti] += tl[ti][d] * wv;
    }
    f32x4 bb = *(const f32x4*)(bi + t * 4);
    for (int ti = 0; ti < 16; ++ti) {
        int n = n0 + ti;
        int tt = n >> 8, hh = (n >> 4) & 15, wwi = n & 15;
        f32x4 pos = *(const f32x4*)(et + (long)tt * 1024 + t * 4)
                  + *(const f32x4*)(eh + (long)hh * 1024 + t * 4)
                  + *(const f32x4*)(ew + (long)wwi * 1024 + t * 4);
        *(f32x4*)(x + (long)n * 1024 + t * 4) = acc[ti] + bb + pos;
    }
}

// ---------------------------------------------------------------------------
__global__ __launch_bounds__(256)
void final_k(const bf16* __restrict__ xn, const float* __restrict__ OW,
             const float* __restrict__ ob, const float* __restrict__ tokens,
             float* __restrict__ out)
{
    __shared__ bf16 xl[8][1024];
    __shared__ float part[4][8][64];
    int t = threadIdx.x;
    int n0 = blockIdx.x * 8;
    for (int i = t; i < 1024; i += 256)
        ((u32x4*)xl)[i] = ((const u32x4*)(xn + (long)n0 * 1024))[i];
    __syncthreads();
    int j = t & 63, s = t >> 6;
    float acc[8] = {0.f, 0.f, 0.f, 0.f, 0.f, 0.f, 0.f, 0.f};
    for (int k = s * 256; k < s * 256 + 256; ++k) {
        float w = OW[(long)k * 64 + j];
#pragma unroll
        for (int ti = 0; ti < 8; ++ti) acc[ti] += (float)xl[ti][k] * w;
    }
    for (int ti = 0; ti < 8; ++ti) part[s][ti][j] = acc[ti];
    __syncthreads();
    if (s == 0) {
        for (int ti = 0; ti < 8; ++ti) {
            int n = n0 + ti;
            float v = part[0][ti][j] + part[1][ti][j] + part[2][ti][j] + part[3][ti][j]
                    + ob[j] + tokens[(long)n * 64 + j];
            int tt = n >> 8, hh = (n >> 4) & 15, wwi = n & 15;
            int c = j >> 2, ph = (j >> 1) & 1, pw = j & 1;
            out[(((long)tt * 16 + c) * 32 + hh * 2 + ph) * 32 + wwi * 2 + pw] = v;
        }
    }
}

// ---------------------------------------------------------------------------
extern "C" void kernel_launch(void* const* d_in, const int* in_sizes, int n_in,
                              void* d_out, int out_size, void* d_ws, size_t ws_size,
                              hipStream_t stream)
{
    const float* latents = (const float*)d_in[0];
    const int*   mask    = (const int*)d_in[1];
    const float* ipw  = (const float*)d_in[2];
    const float* ipb  = (const float*)d_in[3];
    const float* et   = (const float*)d_in[4];
    const float* eh   = (const float*)d_in[5];
    const float* ew   = (const float*)d_in[6];
    const float* lnlw = (const float*)d_in[7];
    const float* lnlb = (const float*)d_in[8];
    const float* lngw = (const float*)d_in[9];
    const float* lngb = (const float*)d_in[10];
    const float* lnfw = (const float*)d_in[11];
    const float* lnfb = (const float*)d_in[12];
    const float* lqkv = (const float*)d_in[13];
    const float* lout = (const float*)d_in[14];
    const float* gqkv = (const float*)d_in[15];
    const float* gout = (const float*)d_in[16];
    const float* w1   = (const float*)d_in[17];
    const float* b1   = (const float*)d_in[18];
    const float* w2   = (const float*)d_in[19];
    const float* b2   = (const float*)d_in[20];
    const float* flw  = (const float*)d_in[21];
    const float* flb  = (const float*)d_in[22];
    const float* opw  = (const float*)d_in[23];
    const float* opb  = (const float*)d_in[24];

    char* p = (char*)d_ws;
    auto alloc = [&](size_t bytes) { char* r = p; p += (bytes + 255) & ~(size_t)255; return r; };
    float* x      = (float*)alloc((size_t)4 << 20);
    bf16*  xn     = (bf16*)alloc((size_t)2 << 20);
    float* qkv    = (float*)alloc((size_t)12 << 20);
    bf16*  ao     = (bf16*)alloc((size_t)2 << 20);
    bf16*  hbuf   = (bf16*)alloc((size_t)8 << 20);
    float* tokens = (float*)alloc((size_t)256 << 10);
    bf16*  Qc     = (bf16*)alloc((size_t)512 << 10);
    bf16*  Kh     = (bf16*)alloc((size_t)2 << 20);
    bf16*  Vt     = (bf16*)alloc((size_t)2 << 20);
    float* S      = (float*)alloc((size_t)16 << 20);
    bf16*  P      = (bf16*)alloc((size_t)8 << 20);
    bf16*  Oc     = (bf16*)alloc((size_t)512 << 10);
    int*   qidx   = (int*)alloc(4096);
    int*   rmap   = (int*)alloc(4096);
    // split-K partial buffers (f32)
    float* loutp = (float*)alloc((size_t)2 * 1024 * 1024 * 4);
    float* goutp = (float*)alloc((size_t)8 * 256 * 1024 * 4);
    float* pvp   = (float*)alloc((size_t)64 * 256 * 64 * 4);
    float* f2p   = (float*)alloc((size_t)4 * 1024 * 1024 * 4);
    // bf16 transposed weights Wt[N][K]
    bf16* lqkvT = (bf16*)alloc((size_t)10 * 3072 * 1024 * 2);
    bf16* loutT = (bf16*)alloc((size_t)10 * 1024 * 1024 * 2);
    bf16* gqkvT = (bf16*)alloc((size_t)10 * 3072 * 1024 * 2);
    bf16* goutT = (bf16*)alloc((size_t)10 * 1024 * 1024 * 2);
    bf16* w1T   = (bf16*)alloc((size_t)10 * 4096 * 1024 * 2);
    bf16* w2T   = (bf16*)alloc((size_t)10 * 1024 * 4096 * 2);

    wtrans_k<<<dim3(48, 16, NL), 256, 0, stream>>>(lqkv, lqkvT, 1024, 3072);
    wtrans_k<<<dim3(16, 16, NL), 256, 0, stream>>>(lout, loutT, 1024, 1024);
    wtrans_k<<<dim3(48, 16, NL), 256, 0, stream>>>(gqkv, gqkvT, 1024, 3072);
    wtrans_k<<<dim3(16, 16, NL), 256, 0, stream>>>(gout, goutT, 1024, 1024);
    wtrans_k<<<dim3(64, 16, NL), 256, 0, stream>>>(w1, w1T, 1024, 4096);
    wtrans_k<<<dim3(16, 64, NL), 256, 0, stream>>>(w2, w2T, 4096, 1024);

    prep_k<<<64, 256, 0, stream>>>(latents, mask, ipw, ipb, et, eh, ew, x, tokens);
    compact_k<<<1, 64, 0, stream>>>(mask, qidx, rmap);

    for (int l = 0; l < NL; ++l) {
        const long wq  = (long)l * 3072 * 1024;
        const long wo  = (long)l * 1024 * 1024;
        const long wf1 = (long)l * 4096 * 1024;

        // lnA: fold previous layer's ffn2 partials (+b2) into x, then LN
        if (l == 0)
            ln_add_k<0, false, false><<<256, 256, 0, stream>>>(
                x, nullptr, 0, nullptr, nullptr, lnlw, lnlb, xn);
        else
            ln_add_k<4, true, false><<<256, 256, 0, stream>>>(
                x, f2p, (long)1024 * 1024, b2 + (l - 1) * 1024, nullptr,
                lnlw + l * HID, lnlb + l * HID, xn);

        // local attention: qkv GEMM writes f32 directly (no split-K)
        gemm_k<EPI_F32, 64, 128, 1><<<dim3(24, 16, 1), 256, 0, stream>>>(
            xn, 1024, 0, lqkvT + wq, 1024, 0, qkv, 3072, 0, nullptr, 1024);
        lattn_k<<<4096, 256, 0, stream>>>(qkv, ao);
        gemm_k<EPI_F32, 64, 128, 2><<<dim3(8, 16, 2), 256, 0, stream>>>(
            ao, 1024, 0, loutT + wo, 1024, 0, loutp, 1024, (long)1024 * 1024, nullptr, 1024);

        // lnB: fold local-out partials
        ln_add_k<2, false, false><<<256, 256, 0, stream>>>(
            x, loutp, (long)1024 * 1024, nullptr, nullptr,
            lngw + l * HID, lngb + l * HID, xn);

        // global attention (masked queries)
        gemm_k<EPI_F32, 64, 128, 1><<<dim3(24, 16, 1), 256, 0, stream>>>(
            xn, 1024, 0, gqkvT + wq, 1024, 0, qkv, 3072, 0, nullptr, 1024);
        qkvbuild_k<<<dim3(20, 16), 256, 0, stream>>>(qkv, qidx, Qc, Kh, Vt);
        gemm_k<EPI_F32, 64, 128, 1><<<dim3(8, 4, 16), 256, 0, stream>>>(
            Qc, 64, (long)256 * 64, Kh, 64, (long)1024 * 64,
            S, 1024, (long)256 * 1024, nullptr, 64);
        softmax_k<<<1024, 256, 0, stream>>>(S, P);
        gemm_k<EPI_F32, 64, 64, 4><<<dim3(1, 4, 64), 256, 0, stream>>>(
            P, 1024, (long)256 * 1024, Vt, 1024, (long)64 * 1024,
            pvp, 64, (long)256 * 64, nullptr, 1024);
        red4pv_k<<<256, 256, 0, stream>>>(pvp, Oc);
        gemm_k<EPI_F32, 64, 128, 8><<<dim3(8, 4, 8), 256, 0, stream>>>(
            Oc, 1024, 0, goutT + wo, 1024, 0, goutp, 1024, (long)256 * 1024, nullptr, 1024);

        // lnC: scatter-fold 8 global-out partials via rmap
        ln_add_k<8, false, true><<<256, 256, 0, stream>>>(
            x, goutp, (long)256 * 1024, nullptr, rmap,
            lnfw + l * HID, lnfb + l * HID, xn);

        // FFN: ffn1 fused bias+GELU -> bf16, no split; ffn2 split-K 4
        gemm_k<EPI_GELU, 64, 128, 1><<<dim3(32, 16, 1), 256, 0, stream>>>(
            xn, 1024, 0, w1T + wf1, 1024, 0, hbuf, 4096, 0, b1 + l * 4096, 1024);
        gemm_k<EPI_F32, 64, 128, 4><<<dim3(8, 16, 4), 256, 0, stream>>>(
            hbuf, 4096, 0, w2T + wf1, 4096, 0, f2p, 1024, (long)1024 * 1024, nullptr, 4096);
    }

    // final LN folds last ffn2 partials (+b2[9])
    ln_add_k<4, true, false><<<256, 256, 0, stream>>>(
        x, f2p, (long)1024 * 1024, b2 + 9 * 1024, nullptr, flw, flb, xn);
    final_k<<<128, 256, 0, stream>>>(xn, opw, opb, tokens, (float*)d_out);
}